// Round 18
// baseline (894.040 us; speedup 1.0000x reference)
//
#include <hip/hip_runtime.h>
#include <math.h>

typedef unsigned short u16;
typedef unsigned int   u32;
typedef __attribute__((ext_vector_type(8))) short bf16x8;
typedef __attribute__((ext_vector_type(4))) float f32x4;

// ---------------- problem constants ----------------------------------------
// B=8, H=W=256, E=64, HID=128, SUB=16, WS=4, NH=4, dh=16, L=4
// tokens: 2048; residual d [tok][256 px][64 ch] fp32 (ch fastest)
// v buffer: [tok][256 px][64 ch] bf16; murs: [tok][mu[64], rs[64]] fp32
#define NTOK  2048
#define TOKSZ 16384ull

#define CBAR() __asm__ __volatile__("" ::: "memory")

__device__ __forceinline__ float bf2f(u16 b) { return __uint_as_float(((u32)b) << 16); }
__device__ __forceinline__ u16 f2bf(float f) {
    u32 u = __float_as_uint(f);
    u += 0x7FFFu + ((u >> 16) & 1u);
    return (u16)(u >> 16);
}
__device__ __forceinline__ float gelu_f(float x) {
    return 0.5f * x * (1.0f + erff(x * 0.70710678118654752440f));
}
__device__ __forceinline__ int shift_tok(int n) {
    int w = n >> 4, s = n & 15;
    int b = w >> 4, wy = (w >> 2) & 3, wx = w & 3;
    int ty = s >> 2, tx = s & 3;
    int gy = ((wy << 2) + ty + 2) & 15;
    int gx = ((wx << 2) + tx + 2) & 15;
    int w2 = (b << 4) + ((gy >> 2) << 2) + (gx >> 2);
    int s2 = ((gy & 3) << 2) + (gx & 3);
    return (w2 << 4) + s2;
}
// XOR-swizzled u16 tile index: row stride 64, chunk = 8 u16
__device__ __forceinline__ int swz(int row, int chunk) {
    return row * 64 + ((chunk ^ (row & 7)) << 3);
}

union U8 { uint4 u; bf16x8 b; };

// ---------------- dtype detection (proven) ---------------------------------
__global__ void detect_kernel(const u16* __restrict__ w1, int* __restrict__ flag) {
    int t = threadIdx.x, bad = 0;
    for (int i = t; i < 640; i += 64) {
        float ax = fabsf(bf2f(w1[i]));
        if (!(ax < 1e3f)) bad = 1;
    }
    unsigned long long m = __ballot(bad);
    if (t == 0) *flag = (m != 0ull) ? 1 : 0;
}

#define NWT 20
struct WArgs { const void* src[NWT]; int off16[NWT + 1]; int f32o[NWT]; };

__global__ __launch_bounds__(256)
void cvt_weights(WArgs a, const int* __restrict__ flag,
                 float* __restrict__ wbufA, u16* __restrict__ wbuf16) {
    int t = blockIdx.x * 256 + threadIdx.x;
    if (t >= a.off16[NWT]) return;
    int s = 0;
    while (a.off16[s + 1] <= t) ++s;
    int idx = t - a.off16[s];
    u16 raw; float v;
    if (*flag) { v = ((const float*)a.src[s])[idx]; raw = f2bf(v); }
    else       { raw = ((const u16*)a.src[s])[idx]; v = bf2f(raw); }
    wbuf16[t] = raw;
    if (a.f32o[s] >= 0) wbufA[a.f32o[s] + idx] = v;
}

// ---------------- embed: coords+3ch -> 128(gelu) -> 64, MFMA, + murs -------
__global__ __launch_bounds__(256, 2)
void embed_mfma(const void* __restrict__ vin, const int* __restrict__ flag,
                const float* __restrict__ W1, const float* __restrict__ b1,
                const u16* __restrict__ W2bf, const float* __restrict__ b2,
                const int* __restrict__ pdsy, const int* __restrict__ pdsx,
                float* __restrict__ d, float* __restrict__ mursg) {
    extern __shared__ char smem[];
    u16* hsT = (u16*)smem;             // [256][64] swizzled
    u16* wl  = (u16*)(smem + 32768);   // [64][64] swizzled
    int n = blockIdx.x, t = threadIdx.x;
    int wv = t >> 6, l = t & 63, m = l & 15, qd = l >> 4;
    int px0 = wv * 64;

    int w = n >> 4, s = n & 15;
    int b = w >> 4, wy = (w >> 2) & 3, wx = w & 3;
    int ty = s >> 2, tx = s & 3;
    int y = ((wy << 2) + ty) * 16 + (t >> 4);
    int x = ((wx << 2) + tx) * 16 + (t & 15);
    int fl = *flag;
    float in0 = ((float)y + 0.5f) * ((float)pdsy[0] * (1.0f / 256.0f));
    float in1 = ((float)x + 0.5f) * ((float)pdsx[0] * (1.0f / 256.0f));
    size_t pix = (size_t)b * 3 * 65536 + (size_t)y * 256 + (size_t)x;
    float in2 = fl ? ((const float*)vin)[pix]          : bf2f(((const u16*)vin)[pix]);
    float in3 = fl ? ((const float*)vin)[pix + 65536]  : bf2f(((const u16*)vin)[pix + 65536]);
    float in4 = fl ? ((const float*)vin)[pix + 131072] : bf2f(((const u16*)vin)[pix + 131072]);

    f32x4 acc[4][4];
    #pragma unroll
    for (int nt = 0; nt < 4; ++nt) {
        float bb = b2[nt * 16 + m];
        #pragma unroll
        for (int mt = 0; mt < 4; ++mt) acc[mt][nt] = {bb, bb, bb, bb};
    }
    for (int half = 0; half < 2; ++half) {
        if (half) __syncthreads();
        for (int h2 = 0; h2 < 64; h2 += 2) {
            int hid = half * 64 + h2;
            float ha = b1[hid] + W1[hid*5]*in0 + W1[hid*5+1]*in1 + W1[hid*5+2]*in2
                     + W1[hid*5+3]*in3 + W1[hid*5+4]*in4;
            float hb2 = b1[hid+1] + W1[hid*5+5]*in0 + W1[hid*5+6]*in1 + W1[hid*5+7]*in2
                     + W1[hid*5+8]*in3 + W1[hid*5+9]*in4;
            u32 pk = (u32)f2bf(gelu_f(ha)) | ((u32)f2bf(gelu_f(hb2)) << 16);
            *(u32*)&hsT[swz(t, h2 >> 3) + (h2 & 7)] = pk;
        }
        #pragma unroll
        for (int r = 0; r < 2; ++r) {
            int u = t + r * 256; int e = u >> 3, c8 = u & 7;
            *(uint4*)&wl[swz(e, c8)] = *(const uint4*)(W2bf + e * 128 + half * 64 + c8 * 8);
        }
        __syncthreads();
        #pragma unroll
        for (int ks = 0; ks < 2; ++ks) {
            U8 af[4], bf[4];
            #pragma unroll
            for (int mt = 0; mt < 4; ++mt)
                af[mt].u = *(const uint4*)&hsT[swz(px0 + mt*16 + m, ks*4 + qd)];
            #pragma unroll
            for (int nt = 0; nt < 4; ++nt)
                bf[nt].u = *(const uint4*)&wl[swz(nt*16 + m, ks*4 + qd)];
            #pragma unroll
            for (int mt = 0; mt < 4; ++mt)
                #pragma unroll
                for (int nt = 0; nt < 4; ++nt)
                    acc[mt][nt] = __builtin_amdgcn_mfma_f32_16x16x32_bf16(
                        af[mt].b, bf[nt].b, acc[mt][nt], 0, 0, 0);
        }
    }
    __syncthreads();
    // ---- instance-norm stats of d -> global murs (for layer-0 attention) --
    float sv[4], qv[4];
    #pragma unroll
    for (int nt = 0; nt < 4; ++nt) {
        float ss = 0.f, qq = 0.f;
        #pragma unroll
        for (int mt = 0; mt < 4; ++mt)
            #pragma unroll
            for (int r = 0; r < 4; ++r) { float xx = acc[mt][nt][r]; ss += xx; qq = fmaf(xx, xx, qq); }
        ss += __shfl_xor(ss, 16); ss += __shfl_xor(ss, 32);
        qq += __shfl_xor(qq, 16); qq += __shfl_xor(qq, 32);
        sv[nt] = ss; qv[nt] = qq;
    }
    float* sarr = (float*)smem;        // [64 ch][4 wv] sums, then +256 sq-sums
    if (qd == 0) {
        #pragma unroll
        for (int nt = 0; nt < 4; ++nt) {
            sarr[(nt*16 + m)*4 + wv] = sv[nt];
            sarr[256 + (nt*16 + m)*4 + wv] = qv[nt];
        }
    }
    __syncthreads();
    if (t < 64) {
        float ss = sarr[t*4] + sarr[t*4+1] + sarr[t*4+2] + sarr[t*4+3];
        float qq = sarr[256+t*4] + sarr[256+t*4+1] + sarr[256+t*4+2] + sarr[256+t*4+3];
        float mu = ss * (1.0f/256.0f);
        float var = qq * (1.0f/256.0f) - mu * mu;
        mursg[(size_t)n * 128 + t] = mu;
        mursg[(size_t)n * 128 + 64 + t] = rsqrtf(var + 1e-5f);
    }
    __syncthreads();
    // ---- epilogue: write d (f32) ----
    float* eps = (float*)smem + wv * 2304;
    float* dp = d + (size_t)n * TOKSZ;
    #pragma unroll
    for (int ch2 = 0; ch2 < 2; ++ch2) {
        if (ch2) CBAR();
        #pragma unroll
        for (int mt = ch2*2; mt < ch2*2+2; ++mt)
            #pragma unroll
            for (int nt = 0; nt < 4; ++nt)
                #pragma unroll
                for (int r = 0; r < 4; ++r)
                    eps[((mt&1)*16 + qd*4 + r) * 68 + nt*16 + m] = acc[mt][nt][r];
        CBAR();
        #pragma unroll
        for (int j = 0; j < 8; ++j) {
            int f = l + 64*j; int row = f >> 4, c4 = f & 15;
            float4 v = *(float4*)&eps[row * 68 + c4 * 4];
            *(float4*)&dp[(px0 + ch2*32 + row) * 64 + c4 * 4] = v;
        }
    }
}

// ---------------- 128x64x64 GEMM helper (32 rows per wave, 4 waves) --------
__device__ __forceinline__ void gemm64h(const u16* xs, const u16* wl, const float* bv4,
                                        int px0w, int m, int qd, u16* dst) {
    f32x4 acc[2][4];
    #pragma unroll
    for (int nt = 0; nt < 4; ++nt) {
        float bb = bv4[nt];
        acc[0][nt] = {bb, bb, bb, bb};
        acc[1][nt] = {bb, bb, bb, bb};
    }
    #pragma unroll
    for (int ks = 0; ks < 2; ++ks) {
        U8 af[2], bfr[4];
        #pragma unroll
        for (int mi = 0; mi < 2; ++mi)
            af[mi].u = *(const uint4*)&xs[swz(px0w + mi*16 + m, ks*4 + qd)];
        #pragma unroll
        for (int nt = 0; nt < 4; ++nt)
            bfr[nt].u = *(const uint4*)&wl[swz(nt*16 + m, ks*4 + qd)];
        #pragma unroll
        for (int mi = 0; mi < 2; ++mi)
            #pragma unroll
            for (int nt = 0; nt < 4; ++nt)
                acc[mi][nt] = __builtin_amdgcn_mfma_f32_16x16x32_bf16(
                    af[mi].b, bfr[nt].b, acc[mi][nt], 0, 0, 0);
    }
    #pragma unroll
    for (int mi = 0; mi < 2; ++mi)
        #pragma unroll
        for (int nt = 0; nt < 4; ++nt)
            #pragma unroll
            for (int r = 0; r < 4; ++r) {
                int R = px0w + mi*16 + qd*4 + r, ch = nt*16 + m;
                dst[swz(R, ch >> 3) + (ch & 7)] = f2bf(acc[mi][nt][r]);
            }
}

// ---------------- fused norm(on-the-fly) + qkv proj + raw scores -----------
// grid (128 windows, 4 px-quarters); 256 thr; 8-px chunks; LDS 81920 B.
// 512 blocks -> 2 co-resident blocks/CU (R17-proven best).
__global__ __launch_bounds__(256, 2)
void scores_qkv(const float* __restrict__ dres, const float* __restrict__ mursg,
                const u16* __restrict__ Wq, const float* __restrict__ bq,
                const u16* __restrict__ Wk, const float* __restrict__ bk,
                const u16* __restrict__ Wv, const float* __restrict__ bv,
                int shifted, float* __restrict__ Ap, u16* __restrict__ vbuf) {
    extern __shared__ char smem[];
    u16* xs  = (u16*)smem;              // [128 rows=tok*8+pxl][64] swz; xhat then v
    u16* qls = (u16*)(smem + 16384);    // q chunk
    u16* kls = (u16*)(smem + 32768);    // k chunk
    u16* wlq = (u16*)(smem + 49152);
    u16* wlk = (u16*)(smem + 57344);
    u16* wlv = (u16*)(smem + 65536);
    float* mloc = (float*)(smem + 73728);   // [16 tok][128] mu|rs
    int w = blockIdx.x, qtr = blockIdx.y, t = threadIdx.x;
    int wv = t >> 6, l = t & 63, m = l & 15, qd = l >> 4;
    int px0w = wv * 32;
    // staging token indices: each thread touches toks {wv, wv+4, wv+8, wv+12}
    int nst[4];
    #pragma unroll
    for (int i8 = 0; i8 < 4; ++i8) {
        int nn = w * 16 + (4 * i8 + wv);
        nst[i8] = shifted ? shift_tok(nn) : nn;
    }
    // mloc load: 2048 floats (inline shift_tok, once per kernel)
    #pragma unroll
    for (int r = 0; r < 8; ++r) {
        int u = t + r * 256;
        int nn = w * 16 + (u >> 7);
        int ni = shifted ? shift_tok(nn) : nn;
        mloc[u] = mursg[(size_t)ni * 128 + (u & 127)];
    }
    #pragma unroll
    for (int r = 0; r < 2; ++r) {
        int u = t + r * 256; int e = u >> 3, c8 = u & 7;
        *(uint4*)&wlq[swz(e, c8)] = *(const uint4*)(Wq + e * 64 + c8 * 8);
        *(uint4*)&wlk[swz(e, c8)] = *(const uint4*)(Wk + e * 64 + c8 * 8);
        *(uint4*)&wlv[swz(e, c8)] = *(const uint4*)(Wv + e * 64 + c8 * 8);
    }
    float bqv[4], bkv[4], bvv[4];
    #pragma unroll
    for (int nt = 0; nt < 4; ++nt) {
        bqv[nt] = bq[nt*16 + m]; bkv[nt] = bk[nt*16 + m]; bvv[nt] = bv[nt*16 + m];
    }
    f32x4 sacc = {0.f, 0.f, 0.f, 0.f};
    __syncthreads();
    for (int ch = 0; ch < 8; ++ch) {
        int pxb = qtr * 64 + ch * 8;
        // stage + normalize chunk: 16 tok x 8 px x 64 ch (fp32 -> bf16 xhat)
        #pragma unroll
        for (int i8 = 0; i8 < 4; ++i8) {
            int u = t + i8 * 256; int row = u >> 3, c8 = u & 7;
            int pxl = row & 7;
            int tok = 4 * i8 + wv;          // == row >> 3
            const float4* gp = (const float4*)
                (dres + (size_t)nst[i8] * TOKSZ + (size_t)(pxb + pxl) * 64 + c8 * 8);
            float4 f0 = gp[0], f1 = gp[1];
            const float4* mp = (const float4*)&mloc[tok * 128 + c8 * 8];
            float4 mu0 = mp[0], mu1 = mp[1];
            const float4* rp = (const float4*)&mloc[tok * 128 + 64 + c8 * 8];
            float4 rs0 = rp[0], rs1 = rp[1];
            uint4 o;
            o.x = (u32)f2bf((f0.x-mu0.x)*rs0.x) | ((u32)f2bf((f0.y-mu0.y)*rs0.y) << 16);
            o.y = (u32)f2bf((f0.z-mu0.z)*rs0.z) | ((u32)f2bf((f0.w-mu0.w)*rs0.w) << 16);
            o.z = (u32)f2bf((f1.x-mu1.x)*rs1.x) | ((u32)f2bf((f1.y-mu1.y)*rs1.y) << 16);
            o.w = (u32)f2bf((f1.z-mu1.z)*rs1.z) | ((u32)f2bf((f1.w-mu1.w)*rs1.w) << 16);
            *(uint4*)&xs[swz(row, c8)] = o;
        }
        __syncthreads();
        // q,k GEMMs -> qls/kls; v GEMM overwrites own wave's xs rows (safe:
        // each wave's A-frag reads only rows [px0w,px0w+32), scatter same range)
        gemm64h(xs, wlq, bqv, px0w, m, qd, qls);
        gemm64h(xs, wlk, bkv, px0w, m, qd, kls);
        gemm64h(xs, wlv, bvv, px0w, m, qd, xs);
        __syncthreads();
        // raw scores: wave wv = head; K = 2px x 16ch per mfma; 4 px-pairs
        #pragma unroll
        for (int p2 = 0; p2 < 4; ++p2) {
            U8 af, bfr;
            int row = m * 8 + p2 * 2 + (qd >> 1);
            int c8 = wv * 2 + (qd & 1);
            af.u  = *(const uint4*)&qls[swz(row, c8)];
            bfr.u = *(const uint4*)&kls[swz(row, c8)];
            sacc = __builtin_amdgcn_mfma_f32_16x16x32_bf16(af.b, bfr.b, sacc, 0, 0, 0);
        }
        // v chunk -> global
        #pragma unroll
        for (int i8 = 0; i8 < 4; ++i8) {
            int u = t + i8 * 256; int row = u >> 3, c8 = u & 7;
            int pxl = row & 7;
            *(uint4*)(vbuf + (size_t)nst[i8] * 16384 + (size_t)(pxb + pxl) * 64 + c8 * 8)
                = *(const uint4*)&xs[swz(row, c8)];
        }
        __syncthreads();                // WAR: next stage overwrites xs
    }
    float* ap = Ap + (size_t)qtr * 131072 + ((size_t)w * 4 + wv) * 256;
    #pragma unroll
    for (int r = 0; r < 4; ++r)
        ap[(qd * 4 + r) * 16 + m] = sacc[r] * (1.0f / 1024.0f);
}

// ---------------- fused softmax + A@v + Wo + residual + MLP + murs ---------
// 512 thr / 8 waves, 32 px rows per wave: per-wave regs = xv[8](32) +
// acc[2][4](32) + misc <= 128 cap of (512,4) -> 2 blocks x 8 waves = 16
// waves/CU (2x the 256-thr version's TLP). LDS 40960; eps 8x1152 = 36864 B;
// stats sarr (64ch x 32 grp x 2) lives in dead-xs region at +2048 B.
__global__ __launch_bounds__(512, 4)
void wo_mlp(const u16* __restrict__ vb, const float* __restrict__ Ap,
            const u16* __restrict__ Wo, const float* __restrict__ bo,
            const u16* __restrict__ W1, const float* __restrict__ b1,
            const u16* __restrict__ W2, const float* __restrict__ b2,
            int shifted, float* __restrict__ dres, float* __restrict__ mursg,
            int wmu) {
    extern __shared__ char smem[];
    u16* xs = (u16*)smem;               // [256][64] swz: o-tile / xhat / h
    u16* wl = (u16*)(smem + 32768);     // [64][64] swz (Wo/W1/W2, loaded late)
    float* As = (float*)(smem + 32768); // [4 heads][16 j] (pre-Wo alias)
    int*  nis = (int*)(smem + 33792);   // 16 (pre-Wo alias)
    float* sarr = (float*)(smem + 2048);    // stats: [64ch][32g] + qarr (xs dead)
    float* murs2 = (float*)smem;            // stats alias of xs[0,512)
    int bid = blockIdx.x;
    int qg = bid >> 7, r7 = bid & 127;
    int n = ((qg << 3) + (r7 & 7)) * 16 + (r7 >> 3);
    int t = threadIdx.x;
    int wv = t >> 6, l = t & 63, m = l & 15, qd = l >> 4;
    int px0 = wv * 32;
    int w = n >> 4, i = n & 15;
    int no = shifted ? shift_tok(n) : n;
    int rbase = l >> 4, c4l = l & 15;
    if (t < 16) { int nn = w * 16 + t; nis[t] = shifted ? shift_tok(nn) : nn; }
    if (t >= 64 && t < 128) {
        int u = t - 64; int h = u >> 4, j = u & 15;
        size_t ai = ((size_t)(w * 4 + h)) * 256 + i * 16 + j;
        float sc = (Ap[ai] + Ap[131072 + ai] + Ap[262144 + ai] + Ap[393216 + ai])
                   * (1.0f / 1024.0f);
        float mx = sc;
        #pragma unroll
        for (int off = 1; off < 16; off <<= 1) mx = fmaxf(mx, __shfl_xor(mx, off, 16));
        float e = expf(sc - mx);
        float ssum = e;
        #pragma unroll
        for (int off = 1; off < 16; off <<= 1) ssum += __shfl_xor(ssum, off, 16);
        As[u] = e / ssum;
    }
    __syncthreads();
    // o-tile = A @ v, written into xs (bf16, swizzled)
    #pragma unroll
    for (int r = 0; r < 4; ++r) {
        int idx = r * 512 + t;
        int px = idx >> 3, c8 = idx & 7, h = c8 >> 1;
        float a0=0,a1=0,a2=0,a3=0,a4=0,a5=0,a6=0,a7=0;
        #pragma unroll
        for (int j = 0; j < 16; ++j) {
            const u16* src = vb + (size_t)nis[j] * 16384 + (size_t)px * 64 + c8 * 8;
            uint4 pv = *(const uint4*)src;
            float aw = As[h * 16 + j];
            a0 = fmaf(aw, __uint_as_float(pv.x << 16), a0);
            a1 = fmaf(aw, __uint_as_float(pv.x & 0xFFFF0000u), a1);
            a2 = fmaf(aw, __uint_as_float(pv.y << 16), a2);
            a3 = fmaf(aw, __uint_as_float(pv.y & 0xFFFF0000u), a3);
            a4 = fmaf(aw, __uint_as_float(pv.z << 16), a4);
            a5 = fmaf(aw, __uint_as_float(pv.z & 0xFFFF0000u), a5);
            a6 = fmaf(aw, __uint_as_float(pv.w << 16), a6);
            a7 = fmaf(aw, __uint_as_float(pv.w & 0xFFFF0000u), a7);
        }
        uint4 o;
        o.x = (u32)f2bf(a0) | ((u32)f2bf(a1) << 16);
        o.y = (u32)f2bf(a2) | ((u32)f2bf(a3) << 16);
        o.z = (u32)f2bf(a4) | ((u32)f2bf(a5) << 16);
        o.w = (u32)f2bf(a6) | ((u32)f2bf(a7) << 16);
        *(uint4*)&xs[swz(px, c8)] = o;
    }
    __syncthreads();                     // o-tile done; As/nis dead
    {
        int e = t >> 3, c8 = t & 7;
        *(uint4*)&wl[swz(e, c8)] = *(const uint4*)(Wo + e * 64 + c8 * 8);
    }
    __syncthreads();
    // GEMM: attnout = Wo · o + bo (32 rows per wave)
    f32x4 acc[2][4];
    #pragma unroll
    for (int nt = 0; nt < 4; ++nt) {
        float bb = bo[nt * 16 + m];
        acc[0][nt] = {bb, bb, bb, bb};
        acc[1][nt] = {bb, bb, bb, bb};
    }
    #pragma unroll
    for (int ks = 0; ks < 2; ++ks) {
        U8 af[2], bf[4];
        #pragma unroll
        for (int mi = 0; mi < 2; ++mi)
            af[mi].u = *(const uint4*)&xs[swz(px0 + mi*16 + m, ks*4 + qd)];
        #pragma unroll
        for (int nt = 0; nt < 4; ++nt)
            bf[nt].u = *(const uint4*)&wl[swz(nt*16 + m, ks*4 + qd)];
        #pragma unroll
        for (int mi = 0; mi < 2; ++mi)
            #pragma unroll
            for (int nt = 0; nt < 4; ++nt)
                acc[mi][nt] = __builtin_amdgcn_mfma_f32_16x16x32_bf16(
                    af[mi].b, bf[nt].b, acc[mi][nt], 0, 0, 0);
    }
    __syncthreads();                     // xs/wl dead -> alias eps
    // handoff: xv = d[no] + attnout (registers, mlp layout); 16 rows per half
    float* eps = (float*)smem + wv * 1152;
    float* dp = dres + (size_t)no * TOKSZ;
    float4 xv[8];
    #pragma unroll
    for (int ch2 = 0; ch2 < 2; ++ch2) {
        if (ch2) CBAR();
        #pragma unroll
        for (int nt = 0; nt < 4; ++nt)
            #pragma unroll
            for (int r = 0; r < 4; ++r)
                eps[(qd*4 + r) * 68 + nt*16 + m] = acc[ch2][nt][r];
        CBAR();
        #pragma unroll
        for (int j = 0; j < 4; ++j) {
            int row = rbase + 4*j;
            float4 dv = *(float4*)&eps[row * 68 + c4l * 4];
            float4 gv = *(const float4*)&dp[(px0 + ch2*16 + row) * 64 + c4l * 4];
            gv.x += dv.x; gv.y += dv.y; gv.z += dv.z; gv.w += dv.w;
            xv[ch2*4 + j] = gv;
        }
    }
    __syncthreads();                     // eps dead before sarr reuse
    // ---- MLP phase: norm stats (32 groups) ----
    float s0=0,s1=0,s2=0,s3=0,q0=0,q1=0,q2=0,q3=0;
    #pragma unroll
    for (int k8 = 0; k8 < 8; ++k8) {
        float4 v = xv[k8];
        s0 += v.x; q0 = fmaf(v.x, v.x, q0);
        s1 += v.y; q1 = fmaf(v.y, v.y, q1);
        s2 += v.z; q2 = fmaf(v.z, v.z, q2);
        s3 += v.w; q3 = fmaf(v.w, v.w, q3);
    }
    int cb = 4 * c4l, g = t >> 4;
    float* qarr = sarr + 2048;
    sarr[(cb+0)*32+g]=s0; sarr[(cb+1)*32+g]=s1; sarr[(cb+2)*32+g]=s2; sarr[(cb+3)*32+g]=s3;
    qarr[(cb+0)*32+g]=q0; qarr[(cb+1)*32+g]=q1; qarr[(cb+2)*32+g]=q2; qarr[(cb+3)*32+g]=q3;
    __syncthreads();
    if (t < 64) {
        float ss = 0.f, qq = 0.f;
        #pragma unroll
        for (int gg = 0; gg < 32; ++gg) { ss += sarr[t*32+gg]; qq += qarr[t*32+gg]; }
        float mu = ss * (1.0f/256.0f);
        float var = qq * (1.0f/256.0f) - mu * mu;
        murs2[t] = mu; murs2[64 + t] = rsqrtf(var + 1e-5f);
    }
    __syncthreads();
    float m0 = murs2[cb], m1 = murs2[cb+1], m2 = murs2[cb+2], m3 = murs2[cb+3];
    float r0 = murs2[64+cb], r1 = murs2[64+cb+1], r2 = murs2[64+cb+2], r3 = murs2[64+cb+3];
    __syncthreads();                     // murs2 reads done before xs writes
    #pragma unroll
    for (int k8 = 0; k8 < 8; ++k8) {
        float4 v = xv[k8];
        int row = px0 + (k8 >> 2) * 16 + rbase + 4 * (k8 & 3);
        uint2 o;
        o.x = (u32)f2bf((v.x-m0)*r0) | ((u32)f2bf((v.y-m1)*r1) << 16);
        o.y = (u32)f2bf((v.z-m2)*r2) | ((u32)f2bf((v.w-m3)*r3) << 16);
        *(uint2*)&xs[swz(row, c4l >> 1) + (c4l & 1) * 4] = o;
    }
    {
        int e = t >> 3, c8 = t & 7;
        *(uint4*)&wl[swz(e, c8)] = *(const uint4*)(W1 + e * 64 + c8 * 8);
    }
    __syncthreads();
    #pragma unroll
    for (int nt = 0; nt < 4; ++nt) {
        float bb = b1[nt * 16 + m];
        acc[0][nt] = {bb, bb, bb, bb};
        acc[1][nt] = {bb, bb, bb, bb};
    }
    #pragma unroll
    for (int ks = 0; ks < 2; ++ks) {
        U8 af[2], bf[4];
        #pragma unroll
        for (int mi = 0; mi < 2; ++mi)
            af[mi].u = *(const uint4*)&xs[swz(px0 + mi*16 + m, ks*4 + qd)];
        #pragma unroll
        for (int nt = 0; nt < 4; ++nt)
            bf[nt].u = *(const uint4*)&wl[swz(nt*16 + m, ks*4 + qd)];
        #pragma unroll
        for (int mi = 0; mi < 2; ++mi)
            #pragma unroll
            for (int nt = 0; nt < 4; ++nt)
                acc[mi][nt] = __builtin_amdgcn_mfma_f32_16x16x32_bf16(
                    af[mi].b, bf[nt].b, acc[mi][nt], 0, 0, 0);
    }
    __syncthreads();
    #pragma unroll
    for (int nt = 0; nt < 4; ++nt) {
        int ch = nt * 16 + m;
        #pragma unroll
        for (int mi = 0; mi < 2; ++mi)
            #pragma unroll
            for (int r = 0; r < 4; ++r) {
                int R = px0 + mi*16 + qd*4 + r;
                xs[swz(R, ch >> 3) + (ch & 7)] = f2bf(gelu_f(acc[mi][nt][r]));
            }
    }
    {
        int e = t >> 3, c8 = t & 7;
        *(uint4*)&wl[swz(e, c8)] = *(const uint4*)(W2 + e * 64 + c8 * 8);
    }
    __syncthreads();
    #pragma unroll
    for (int nt = 0; nt < 4; ++nt) {
        float bb = b2[nt * 16 + m];
        acc[0][nt] = {bb, bb, bb, bb};
        acc[1][nt] = {bb, bb, bb, bb};
    }
    #pragma unroll
    for (int ks = 0; ks < 2; ++ks) {
        U8 af[2], bf[4];
        #pragma unroll
        for (int mi = 0; mi < 2; ++mi)
            af[mi].u = *(const uint4*)&xs[swz(px0 + mi*16 + m, ks*4 + qd)];
        #pragma unroll
        for (int nt = 0; nt < 4; ++nt)
            bf[nt].u = *(const uint4*)&wl[swz(nt*16 + m, ks*4 + qd)];
        #pragma unroll
        for (int mi = 0; mi < 2; ++mi)
            #pragma unroll
            for (int nt = 0; nt < 4; ++nt)
                acc[mi][nt] = __builtin_amdgcn_mfma_f32_16x16x32_bf16(
                    af[mi].b, bf[nt].b, acc[mi][nt], 0, 0, 0);
    }
    __syncthreads();
    #pragma unroll
    for (int ch2 = 0; ch2 < 2; ++ch2) {
        if (ch2) CBAR();
        #pragma unroll
        for (int nt = 0; nt < 4; ++nt)
            #pragma unroll
            for (int r = 0; r < 4; ++r)
                eps[(qd*4 + r) * 68 + nt*16 + m] = acc[ch2][nt][r];
        CBAR();
        #pragma unroll
        for (int j = 0; j < 4; ++j) {
            int row = rbase + 4*j;
            float4 dv = *(float4*)&eps[row * 68 + c4l * 4];
            float4 bs = xv[ch2*4 + j];                // residual from registers
            bs.x += dv.x; bs.y += dv.y; bs.z += dv.z; bs.w += dv.w;
            xv[ch2*4 + j] = bs;                       // final d
            *(float4*)&dp[(px0 + ch2*16 + row) * 64 + c4l * 4] = bs;
        }
    }
    if (wmu) {
        __syncthreads();                // eps reads done before sarr reuse
        float t0=0,t1=0,t2=0,t3=0,u0=0,u1=0,u2=0,u3=0;
        #pragma unroll
        for (int k8 = 0; k8 < 8; ++k8) {
            float4 v = xv[k8];
            t0 += v.x; u0 = fmaf(v.x, v.x, u0);
            t1 += v.y; u1 = fmaf(v.y, v.y, u1);
            t2 += v.z; u2 = fmaf(v.z, v.z, u2);
            t3 += v.w; u3 = fmaf(v.w, v.w, u3);
        }
        sarr[(cb+0)*32+g]=t0; sarr[(cb+1)*32+g]=t1; sarr[(cb+2)*32+g]=t2; sarr[(cb+3)*32+g]=t3;
        qarr[(cb+0)*32+g]=u0; qarr[(cb+1)*32+g]=u1; qarr[(cb+2)*32+g]=u2; qarr[(cb+3)*32+g]=u3;
        __syncthreads();
        if (t < 64) {
            float ss = 0.f, qq = 0.f;
            #pragma unroll
            for (int gg = 0; gg < 32; ++gg) { ss += sarr[t*32+gg]; qq += qarr[t*32+gg]; }
            float mu = ss * (1.0f/256.0f);
            float var = qq * (1.0f/256.0f) - mu * mu;
            mursg[(size_t)no * 128 + t] = mu;
            mursg[(size_t)no * 128 + 64 + t] = rsqrtf(var + 1e-5f);
        }
    }
}

// ---------------- layer 3: softmax + A@v + Wo + residual + MLP + out MLP ---
// wo_mlp front (no d write) + mlp_out tail; physical token = no (shifted).
// LDS exactly 40960; launch_bounds (256,2).
__global__ __launch_bounds__(256, 2)
void wo_mlp_out(const u16* __restrict__ vb, const float* __restrict__ Ap,
                const u16* __restrict__ Wo, const float* __restrict__ bo,
                const u16* __restrict__ W1, const float* __restrict__ b1,
                const u16* __restrict__ W2, const float* __restrict__ b2,
                int shifted, const float* __restrict__ dres,
                const u16* __restrict__ oW1, const float* __restrict__ ob1,
                const float* __restrict__ oW2, const float* __restrict__ ob2,
                void* __restrict__ outp, const int* __restrict__ flag) {
    extern __shared__ char smem[];
    u16* xs = (u16*)smem;               // [256][64] swz: o-tile / xhat / h / d16
    u16* wl = (u16*)(smem + 32768);     // [64][64] swz (Wo/W1/W2/oW1)
    float* As = (float*)(smem + 32768); // [4 heads][16 j] (pre-Wo alias)
    int*  nis = (int*)(smem + 33792);   // 16 (pre-Wo alias)
    float* sarr = (float*)(smem + 32768);   // stats alias of wl
    float* murs2 = (float*)smem;            // stats alias of xs[0,512)
    int bid = blockIdx.x;
    int qg = bid >> 7, r7 = bid & 127;
    int n = ((qg << 3) + (r7 & 7)) * 16 + (r7 >> 3);
    int t = threadIdx.x;
    int wv = t >> 6, l = t & 63, m = l & 15, qd = l >> 4;
    int px0 = wv * 64;
    int w = n >> 4, i = n & 15;
    int no = shifted ? shift_tok(n) : n;
    int rbase = l >> 4, c4l = l & 15;
    if (t < 16) { int nn = w * 16 + t; nis[t] = shifted ? shift_tok(nn) : nn; }
    if (t >= 64 && t < 128) {
        int u = t - 64; int h = u >> 4, j = u & 15;
        size_t ai = ((size_t)(w * 4 + h)) * 256 + i * 16 + j;
        float sc = (Ap[ai] + Ap[131072 + ai] + Ap[262144 + ai] + Ap[393216 + ai])
                   * (1.0f / 1024.0f);
        float mx = sc;
        #pragma unroll
        for (int off = 1; off < 16; off <<= 1) mx = fmaxf(mx, __shfl_xor(mx, off, 16));
        float e = expf(sc - mx);
        float ssum = e;
        #pragma unroll
        for (int off = 1; off < 16; off <<= 1) ssum += __shfl_xor(ssum, off, 16);
        As[u] = e / ssum;
    }
    __syncthreads();
    // o-tile = A @ v
    #pragma unroll
    for (int r = 0; r < 8; ++r) {
        int idx = r * 256 + t;
        int px = idx >> 3, c8 = idx & 7, h = c8 >> 1;
        float a0=0,a1=0,a2=0,a3=0,a4=0,a5=0,a6=0,a7=0;
        #pragma unroll
        for (int j = 0; j < 16; ++j) {
            const u16* src = vb + (size_t)nis[j] * 16384 + (size_t)px * 64 + c8 * 8;
            uint4 pv = *(const uint4*)src;
            float aw = As[h * 16 + j];
            a0 = fmaf(aw, __uint_as_float(pv.x << 16), a0);
            a1 = fmaf(aw, __uint_as_float(pv.x & 0xFFFF0000u), a1);
            a2 = fmaf(aw, __uint_as_float(pv.y << 16), a2);
            a3 = fmaf(aw, __uint_as_float(pv.y & 0xFFFF0000u), a3);
            a4 = fmaf(aw, __uint_as_float(pv.z << 16), a4);
            a5 = fmaf(aw, __uint_as_float(pv.z & 0xFFFF0000u), a5);
            a6 = fmaf(aw, __uint_as_float(pv.w << 16), a6);
            a7 = fmaf(aw, __uint_as_float(pv.w & 0xFFFF0000u), a7);
        }
        uint4 o;
        o.x = (u32)f2bf(a0) | ((u32)f2bf(a1) << 16);
        o.y = (u32)f2bf(a2) | ((u32)f2bf(a3) << 16);
        o.z = (u32)f2bf(a4) | ((u32)f2bf(a5) << 16);
        o.w = (u32)f2bf(a6) | ((u32)f2bf(a7) << 16);
        *(uint4*)&xs[swz(px, c8)] = o;
    }
    __syncthreads();                     // o-tile done; As/nis dead
    #pragma unroll
    for (int r = 0; r < 2; ++r) {
        int u = t + r * 256;
        int e = u >> 3, c8 = u & 7;
        *(uint4*)&wl[swz(e, c8)] = *(const uint4*)(Wo + e * 64 + c8 * 8);
    }
    __syncthreads();
    // GEMM: attnout = Wo · o + bo
    f32x4 acc[4][4];
    #pragma unroll
    for (int nt = 0; nt < 4; ++nt) {
        float bb = bo[nt * 16 + m];
        #pragma unroll
        for (int mt = 0; mt < 4; ++mt) acc[mt][nt] = {bb, bb, bb, bb};
    }
    #pragma unroll
    for (int ks = 0; ks < 2; ++ks) {
        U8 af[4], bf[4];
        #pragma unroll
        for (int mt = 0; mt < 4; ++mt)
            af[mt].u = *(const uint4*)&xs[swz(px0 + mt*16 + m, ks*4 + qd)];
        #pragma unroll
        for (int nt = 0; nt < 4; ++nt)
            bf[nt].u = *(const uint4*)&wl[swz(nt*16 + m, ks*4 + qd)];
        #pragma unroll
        for (int mt = 0; mt < 4; ++mt)
            #pragma unroll
            for (int nt = 0; nt < 4; ++nt)
                acc[mt][nt] = __builtin_amdgcn_mfma_f32_16x16x32_bf16(
                    af[mt].b, bf[nt].b, acc[mt][nt], 0, 0, 0);
    }
    __syncthreads();                     // xs/wl dead -> alias eps
    // handoff: xv = d[no] + attnout (registers, mlp layout)
    float* eps = (float*)smem + wv * 2304;
    const float* dp = dres + (size_t)no * TOKSZ;
    float4 xv[2][8];
    #pragma unroll
    for (int ch2 = 0; ch2 < 2; ++ch2) {
        if (ch2) CBAR();
        #pragma unroll
        for (int mt = ch2*2; mt < ch2*2+2; ++mt)
            #pragma unroll
            for (int nt = 0; nt < 4; ++nt)
                #pragma unroll
                for (int r = 0; r < 4; ++r)
                    eps[((mt&1)*16 + qd*4 + r) * 68 + nt*16 + m] = acc[mt][nt][r];
        CBAR();
        #pragma unroll
        for (int j = 0; j < 8; ++j) {
            int row = rbase + 4*j;
            float4 dv = *(float4*)&eps[row * 68 + c4l * 4];
            float4 gv = *(const float4*)&dp[(px0 + ch2*32 + row) * 64 + c4l * 4];
            gv.x += dv.x; gv.y += dv.y; gv.z += dv.z; gv.w += dv.w;
            xv[ch2][j] = gv;
        }
    }
    __syncthreads();                     // eps dead before sarr reuse
    // ---- MLP phase: norm stats ----
    float s0=0,s1=0,s2=0,s3=0,q0=0,q1=0,q2=0,q3=0;
    #pragma unroll
    for (int ch2 = 0; ch2 < 2; ++ch2)
        #pragma unroll
        for (int j = 0; j < 8; ++j) {
            float4 v = xv[ch2][j];
            s0 += v.x; q0 = fmaf(v.x, v.x, q0);
            s1 += v.y; q1 = fmaf(v.y, v.y, q1);
            s2 += v.z; q2 = fmaf(v.z, v.z, q2);
            s3 += v.w; q3 = fmaf(v.w, v.w, q3);
        }
    int cb = 4 * c4l, g = t >> 4;
    float* qarr = sarr + 1024;
    sarr[(cb+0)*16+g]=s0; sarr[(cb+1)*16+g]=s1; sarr[(cb+2)*16+g]=s2; sarr[(cb+3)*16+g]=s3;
    qarr[(cb+0)*16+g]=q0; qarr[(cb+1)*16+g]=q1; qarr[(cb+2)*16+g]=q2; qarr[(cb+3)*16+g]=q3;
    __syncthreads();
    if (t < 64) {
        float ss = 0.f, qq = 0.f;
        #pragma unroll
        for (int gg = 0; gg < 16; ++gg) { ss += sarr[t*16+gg]; qq += qarr[t*16+gg]; }
        float mu = ss * (1.0f/256.0f);
        float var = qq * (1.0f/256.0f) - mu * mu;
        murs2[t] = mu; murs2[64 + t] = rsqrtf(var + 1e-5f);
    }
    __syncthreads();
    float m0 = murs2[cb], m1 = murs2[cb+1], m2 = murs2[cb+2], m3 = murs2[cb+3];
    float r0 = murs2[64+cb], r1 = murs2[64+cb+1], r2 = murs2[64+cb+2], r3 = murs2[64+cb+3];
    __syncthreads();                     // murs2 reads done before xs writes
    #pragma unroll
    for (int ch2 = 0; ch2 < 2; ++ch2)
        #pragma unroll
        for (int j = 0; j < 8; ++j) {
            float4 v = xv[ch2][j];
            int row = px0 + ch2*32 + rbase + 4*j;
            uint2 o;
            o.x = (u32)f2bf((v.x-m0)*r0) | ((u32)f2bf((v.y-m1)*r1) << 16);
            o.y = (u32)f2bf((v.z-m2)*r2) | ((u32)f2bf((v.w-m3)*r3) << 16);
            *(uint2*)&xs[swz(row, c4l >> 1) + (c4l & 1) * 4] = o;
        }
    #pragma unroll
    for (int r = 0; r < 2; ++r) {
        int u = t + r * 256;
        int e = u >> 3, c8 = u & 7;
        *(uint4*)&wl[swz(e, c8)] = *(const uint4*)(W1 + e * 64 + c8 * 8);
    }
    __syncthreads();
    #pragma unroll
    for (int nt = 0; nt < 4; ++nt) {
        float bb = b1[nt * 16 + m];
        #pragma unroll
        for (int mt = 0; mt < 4; ++mt) acc[mt][nt] = {bb, bb, bb, bb};
    }
    #pragma unroll
    for (int ks = 0; ks < 2; ++ks) {
        U8 af[4], bf[4];
        #pragma unroll
        for (int mt = 0; mt < 4; ++mt)
            af[mt].u = *(const uint4*)&xs[swz(px0 + mt*16 + m, ks*4 + qd)];
        #pragma unroll
        for (int nt = 0; nt < 4; ++nt)
            bf[nt].u = *(const uint4*)&wl[swz(nt*16 + m, ks*4 + qd)];
        #pragma unroll
        for (int mt = 0; mt < 4; ++mt)
            #pragma unroll
            for (int nt = 0; nt < 4; ++nt)
                acc[mt][nt] = __builtin_amdgcn_mfma_f32_16x16x32_bf16(
                    af[mt].b, bf[nt].b, acc[mt][nt], 0, 0, 0);
    }
    __syncthreads();
    #pragma unroll
    for (int nt = 0; nt < 4; ++nt) {
        int ch = nt * 16 + m;
        #pragma unroll
        for (int mt = 0; mt < 4; ++mt)
            #pragma unroll
            for (int r = 0; r < 4; ++r) {
                int R = px0 + mt*16 + qd*4 + r;
                xs[swz(R, ch >> 3) + (ch & 7)] = f2bf(gelu_f(acc[mt][nt][r]));
            }
    }
    #pragma unroll
    for (int r = 0; r < 2; ++r) {
        int u = t + r * 256;
        int e = u >> 3, c8 = u & 7;
        *(uint4*)&wl[swz(e, c8)] = *(const uint4*)(W2 + e * 64 + c8 * 8);
    }
    __syncthreads();
    #pragma unroll
    for (int nt = 0; nt < 4; ++nt) {
        float bb = b2[nt * 16 + m];
        #pragma unroll
        for (int mt = 0; mt < 4; ++mt) acc[mt][nt] = {bb, bb, bb, bb};
    }
    #pragma unroll
    for (int ks = 0; ks < 2; ++ks) {
        U8 af[4], bf[4];
        #pragma unroll
        for (int mt = 0; mt < 4; ++mt)
            af[mt].u = *(const uint4*)&xs[swz(px0 + mt*16 + m, ks*4 + qd)];
        #pragma unroll
        for (int nt = 0; nt < 4; ++nt)
            bf[nt].u = *(const uint4*)&wl[swz(nt*16 + m, ks*4 + qd)];
        #pragma unroll
        for (int mt = 0; mt < 4; ++mt)
            #pragma unroll
            for (int nt = 0; nt < 4; ++nt)
                acc[mt][nt] = __builtin_amdgcn_mfma_f32_16x16x32_bf16(
                    af[mt].b, bf[nt].b, acc[mt][nt], 0, 0, 0);
    }
    __syncthreads();
    // residual add in registers; final d stays local (never written to HBM)
    #pragma unroll
    for (int ch2 = 0; ch2 < 2; ++ch2) {
        if (ch2) CBAR();
        #pragma unroll
        for (int mt = ch2*2; mt < ch2*2+2; ++mt)
            #pragma unroll
            for (int nt = 0; nt < 4; ++nt)
                #pragma unroll
                for (int r = 0; r < 4; ++r)
                    eps[((mt&1)*16 + qd*4 + r) * 68 + nt*16 + m] = acc[mt][nt][r];
        CBAR();
        #pragma unroll
        for (int j = 0; j < 8; ++j) {
            int row = rbase + 4*j;
            float4 dv = *(float4*)&eps[row * 68 + c4l * 4];
            float4 bs = xv[ch2][j];
            bs.x += dv.x; bs.y += dv.y; bs.z += dv.z; bs.w += dv.w;
            xv[ch2][j] = bs;
        }
    }
    __syncthreads();                    // eps dead; stage d(bf16) -> xs
    #pragma unroll
    for (int ch2 = 0; ch2 < 2; ++ch2)
        #pragma unroll
        for (int j = 0; j < 8; ++j) {
            float4 v = xv[ch2][j];
            int row = px0 + ch2*32 + rbase + 4*j;
            uint2 o;
            o.x = (u32)f2bf(v.x) | ((u32)f2bf(v.y) << 16);
            o.y = (u32)f2bf(v.z) | ((u32)f2bf(v.w) << 16);
            *(uint2*)&xs[swz(row, c4l >> 1) + (c4l & 1) * 4] = o;
        }
    __syncthreads();
    // ---- output MLP: 64 -> 128(gelu) -> 1, M-halved GEMM passes ----
    float val[4][4];
    #pragma unroll
    for (int mt = 0; mt < 4; ++mt)
        #pragma unroll
        for (int r = 0; r < 4; ++r) val[mt][r] = 0.f;
    for (int nh = 0; nh < 2; ++nh) {
        if (nh) __syncthreads();
        #pragma unroll
        for (int r = 0; r < 2; ++r) {
            int u = t + r * 256;
            int e = u >> 3, c8 = u & 7;
            *(uint4*)&wl[swz(e, c8)] = *(const uint4*)(oW1 + (size_t)nh * 4096 + e * 64 + c8 * 8);
        }
        __syncthreads();
        float w2v[4];
        #pragma unroll
        for (int nt = 0; nt < 4; ++nt) w2v[nt] = oW2[nh * 64 + nt * 16 + m];
        #pragma unroll
        for (int mtp = 0; mtp < 2; ++mtp) {
            f32x4 oacc[2][4];
            #pragma unroll
            for (int nt = 0; nt < 4; ++nt) {
                float bb = ob1[nh * 64 + nt * 16 + m];
                oacc[0][nt] = {bb, bb, bb, bb};
                oacc[1][nt] = {bb, bb, bb, bb};
            }
            #pragma unroll
            for (int ks = 0; ks < 2; ++ks) {
                U8 af[2], bf[4];
                #pragma unroll
                for (int mi = 0; mi < 2; ++mi)
                    af[mi].u = *(const uint4*)&xs[swz(px0 + (2*mtp+mi)*16 + m, ks*4 + qd)];
                #pragma unroll
                for (int nt = 0; nt < 4; ++nt)
                    bf[nt].u = *(const uint4*)&wl[swz(nt*16 + m, ks*4 + qd)];
                #pragma unroll
                for (int mi = 0; mi < 2; ++mi)
                    #pragma unroll
                    for (int nt = 0; nt < 4; ++nt)
                        oacc[mi][nt] = __builtin_amdgcn_mfma_f32_16x16x32_bf16(
                            af[mi].b, bf[nt].b, oacc[mi][nt], 0, 0, 0);
            }
            #pragma unroll
            for (int mi = 0; mi < 2; ++mi)
                #pragma unroll
                for (int r = 0; r < 4; ++r) {
                    float p = 0.f;
                    #pragma unroll
                    for (int nt = 0; nt < 4; ++nt)
                        p = fmaf(gelu_f(oacc[mi][nt][r]), w2v[nt], p);
                    val[2*mtp + mi][r] += p;
                }
        }
    }
    __syncthreads();
    float* red = (float*)smem;                 // [256][17]
    #pragma unroll
    for (int mt = 0; mt < 4; ++mt)
        #pragma unroll
        for (int r = 0; r < 4; ++r)
            red[(px0 + mt*16 + qd*4 + r) * 17 + m] = val[mt][r];
    __syncthreads();
    float a = ob2[0];
    #pragma unroll
    for (int j = 0; j < 16; ++j) a += red[t * 17 + j];
    // output coords from PHYSICAL token no
    int wp = no >> 4, sp = no & 15;
    int b = wp >> 4, wy = (wp >> 2) & 3, wx = wp & 3;
    int ty = sp >> 2, tx = sp & 3;
    int y = ((wy << 2) + ty) * 16 + (t >> 4);
    int x = ((wx << 2) + tx) * 16 + (t & 15);
    size_t oi = (size_t)b * 65536 + (size_t)y * 256 + (size_t)x;
    if (*flag) ((float*)outp)[oi] = a;
    else       ((u16*)outp)[oi] = f2bf(a);
}

// ---------------- host launch ----------------------------------------------
extern "C" void kernel_launch(void* const* d_in, const int* in_sizes, int n_in,
                              void* d_out, int out_size, void* d_ws, size_t ws_size,
                              hipStream_t stream) {
    (void)n_in; (void)out_size; (void)ws_size;
    const int* pdsy = (const int*)d_in[21];
    const int* pdsx = (const int*)d_in[22];

    // layout (~205 MB, under proven 235.65 MB); Ap 4 quarter-partials
    char* wsb = (char*)d_ws;
    float* bufd  = (float*)wsb;                       // 134217728
    u16*  vbuf   = (u16*)(wsb + 134217728ull);        // 67108864
    float* Ap    = (float*)(wsb + 201326592ull);      // 2097152 (4 x 131072 fl)
    float* mursg = (float*)(wsb + 203423744ull);      // 1048576 ([tok][mu64|rs64])
    float* wbufA = (float*)(wsb + 204472320ull);      // 10752
    u16* wbuf16  = (u16*)(wsb + 204483072ull);        // ~234752
    int* flag    = (int*)(wsb + 204718080ull);

    const int f32set[12] = {1, 2, 4, 6, 8, 10, 12, 14, 16, 18, 19, 20};
    WArgs wa;
    int off16[NWT + 1]; off16[0] = 0;
    int c32[NWT + 1];
    int fo = 0;
    for (int i = 0; i < NWT; ++i) {
        int di = i + 1;
        wa.src[i] = d_in[di];
        off16[i + 1] = off16[i] + in_sizes[di];
        wa.off16[i] = off16[i];
        int isf = 0;
        for (int j = 0; j < 12; ++j) if (f32set[j] == di) isf = 1;
        wa.f32o[i] = isf ? fo : -1;
        c32[di] = isf ? fo : -1;
        if (isf) fo += in_sizes[di];
    }
    wa.off16[NWT] = off16[NWT];

    detect_kernel<<<1, 64, 0, stream>>>((const u16*)d_in[1], flag);
    cvt_weights<<<(off16[NWT] + 255) / 256, 256, 0, stream>>>(wa, flag, wbufA, wbuf16);

    const float* f_inpW1 = wbufA + c32[1];
    const float* f_inpb1 = wbufA + c32[2];
    const float* f_inpb2 = wbufA + c32[4];
    const float* f_bq  = wbufA + c32[6];
    const float* f_bk  = wbufA + c32[8];
    const float* f_bv  = wbufA + c32[10];
    const float* f_bo  = wbufA + c32[12];
    const float* f_mb1 = wbufA + c32[14];
    const float* f_mb2 = wbufA + c32[16];
    const float* f_ob1 = wbufA + c32[18];
    const float* f_oW2 = wbufA + c32[19];
    const float* f_ob2 = wbufA + c32[20];
    const u16* h_inpW2 = wbuf16 + off16[2];
    const u16* h_Wq  = wbuf16 + off16[4];
    const u16* h_Wk  = wbuf16 + off16[6];
    const u16* h_Wv  = wbuf16 + off16[8];
    const u16* h_Wo  = wbuf16 + off16[10];
    const u16* h_mW1 = wbuf16 + off16[12];
    const u16* h_mW2 = wbuf16 + off16[14];
    const u16* h_oW1 = wbuf16 + off16[16];

    embed_mfma<<<NTOK, 256, 40960, stream>>>(d_in[0], flag, f_inpW1, f_inpb1,
                                             h_inpW2, f_inpb2, pdsy, pdsx,
                                             bufd, mursg);

    for (int l = 0; l < 4; ++l) {
        int sh = l & 1;
        const u16* Wql = h_Wq + l * 4096;  const float* bql = f_bq + l * 64;
        const u16* Wkl = h_Wk + l * 4096;  const float* bkl = f_bk + l * 64;
        const u16* Wvl = h_Wv + l * 4096;  const float* bvl = f_bv + l * 64;
        const u16* Wol = h_Wo + l * 4096;  const float* bol = f_bo + l * 64;
        const u16* W1l = h_mW1 + l * 4096; const float* b1l = f_mb1 + l * 64;
        const u16* W2l = h_mW2 + l * 4096; const float* b2l = f_mb2 + l * 64;

        scores_qkv<<<dim3(128, 4), 256, 81920, stream>>>(
            bufd, mursg, Wql, bql, Wkl, bkl, Wvl, bvl, sh, Ap, vbuf);
        if (l < 3) {
            wo_mlp<<<NTOK, 512, 40960, stream>>>(vbuf, Ap, Wol, bol,
                                                 W1l, b1l, W2l, b2l,
                                                 sh, bufd, mursg, 1);
        } else {
            wo_mlp_out<<<NTOK, 256, 40960, stream>>>(vbuf, Ap, Wol, bol,
                                                     W1l, b1l, W2l, b2l,
                                                     sh, bufd,
                                                     h_oW1, f_ob1, f_oW2, f_ob2,
                                                     d_out, flag);
        }
    }
}

// Round 19
// 847.377 us; speedup vs baseline: 1.0551x; 1.0551x over previous
//
#include <hip/hip_runtime.h>
#include <math.h>

typedef unsigned short u16;
typedef unsigned int   u32;
typedef __attribute__((ext_vector_type(8))) short bf16x8;
typedef __attribute__((ext_vector_type(4))) float f32x4;

// ---------------- problem constants ----------------------------------------
// B=8, H=W=256, E=64, HID=128, SUB=16, WS=4, NH=4, dh=16, L=4
// tokens: 2048; residual d [tok][256 px][64 ch] fp32 (ch fastest)
// v buffer: [tok][256 px][64 ch] bf16; murs: [tok][mu[64], rs[64]] fp32
#define NTOK  2048
#define TOKSZ 16384ull

#define CBAR() __asm__ __volatile__("" ::: "memory")

__device__ __forceinline__ float bf2f(u16 b) { return __uint_as_float(((u32)b) << 16); }
__device__ __forceinline__ u16 f2bf(float f) {
    u32 u = __float_as_uint(f);
    u += 0x7FFFu + ((u >> 16) & 1u);
    return (u16)(u >> 16);
}
__device__ __forceinline__ float gelu_f(float x) {
    return 0.5f * x * (1.0f + erff(x * 0.70710678118654752440f));
}
__device__ __forceinline__ int shift_tok(int n) {
    int w = n >> 4, s = n & 15;
    int b = w >> 4, wy = (w >> 2) & 3, wx = w & 3;
    int ty = s >> 2, tx = s & 3;
    int gy = ((wy << 2) + ty + 2) & 15;
    int gx = ((wx << 2) + tx + 2) & 15;
    int w2 = (b << 4) + ((gy >> 2) << 2) + (gx >> 2);
    int s2 = ((gy & 3) << 2) + (gx & 3);
    return (w2 << 4) + s2;
}
// XOR-swizzled u16 tile index: row stride 64, chunk = 8 u16
__device__ __forceinline__ int swz(int row, int chunk) {
    return row * 64 + ((chunk ^ (row & 7)) << 3);
}

union U8 { uint4 u; bf16x8 b; };

// ---------------- dtype detection (proven) ---------------------------------
__global__ void detect_kernel(const u16* __restrict__ w1, int* __restrict__ flag) {
    int t = threadIdx.x, bad = 0;
    for (int i = t; i < 640; i += 64) {
        float ax = fabsf(bf2f(w1[i]));
        if (!(ax < 1e3f)) bad = 1;
    }
    unsigned long long m = __ballot(bad);
    if (t == 0) *flag = (m != 0ull) ? 1 : 0;
}

#define NWT 20
struct WArgs { const void* src[NWT]; int off16[NWT + 1]; int f32o[NWT]; };

__global__ __launch_bounds__(256)
void cvt_weights(WArgs a, const int* __restrict__ flag,
                 float* __restrict__ wbufA, u16* __restrict__ wbuf16) {
    int t = blockIdx.x * 256 + threadIdx.x;
    if (t >= a.off16[NWT]) return;
    int s = 0;
    while (a.off16[s + 1] <= t) ++s;
    int idx = t - a.off16[s];
    u16 raw; float v;
    if (*flag) { v = ((const float*)a.src[s])[idx]; raw = f2bf(v); }
    else       { raw = ((const u16*)a.src[s])[idx]; v = bf2f(raw); }
    wbuf16[t] = raw;
    if (a.f32o[s] >= 0) wbufA[a.f32o[s] + idx] = v;
}

// ---------------- embed: coords+3ch -> 128(gelu) -> 64, MFMA, + murs -------
__global__ __launch_bounds__(256, 2)
void embed_mfma(const void* __restrict__ vin, const int* __restrict__ flag,
                const float* __restrict__ W1, const float* __restrict__ b1,
                const u16* __restrict__ W2bf, const float* __restrict__ b2,
                const int* __restrict__ pdsy, const int* __restrict__ pdsx,
                float* __restrict__ d, float* __restrict__ mursg) {
    extern __shared__ char smem[];
    u16* hsT = (u16*)smem;             // [256][64] swizzled
    u16* wl  = (u16*)(smem + 32768);   // [64][64] swizzled
    int n = blockIdx.x, t = threadIdx.x;
    int wv = t >> 6, l = t & 63, m = l & 15, qd = l >> 4;
    int px0 = wv * 64;

    int w = n >> 4, s = n & 15;
    int b = w >> 4, wy = (w >> 2) & 3, wx = w & 3;
    int ty = s >> 2, tx = s & 3;
    int y = ((wy << 2) + ty) * 16 + (t >> 4);
    int x = ((wx << 2) + tx) * 16 + (t & 15);
    int fl = *flag;
    float in0 = ((float)y + 0.5f) * ((float)pdsy[0] * (1.0f / 256.0f));
    float in1 = ((float)x + 0.5f) * ((float)pdsx[0] * (1.0f / 256.0f));
    size_t pix = (size_t)b * 3 * 65536 + (size_t)y * 256 + (size_t)x;
    float in2 = fl ? ((const float*)vin)[pix]          : bf2f(((const u16*)vin)[pix]);
    float in3 = fl ? ((const float*)vin)[pix + 65536]  : bf2f(((const u16*)vin)[pix + 65536]);
    float in4 = fl ? ((const float*)vin)[pix + 131072] : bf2f(((const u16*)vin)[pix + 131072]);

    f32x4 acc[4][4];
    #pragma unroll
    for (int nt = 0; nt < 4; ++nt) {
        float bb = b2[nt * 16 + m];
        #pragma unroll
        for (int mt = 0; mt < 4; ++mt) acc[mt][nt] = {bb, bb, bb, bb};
    }
    for (int half = 0; half < 2; ++half) {
        if (half) __syncthreads();
        for (int h2 = 0; h2 < 64; h2 += 2) {
            int hid = half * 64 + h2;
            float ha = b1[hid] + W1[hid*5]*in0 + W1[hid*5+1]*in1 + W1[hid*5+2]*in2
                     + W1[hid*5+3]*in3 + W1[hid*5+4]*in4;
            float hb2 = b1[hid+1] + W1[hid*5+5]*in0 + W1[hid*5+6]*in1 + W1[hid*5+7]*in2
                     + W1[hid*5+8]*in3 + W1[hid*5+9]*in4;
            u32 pk = (u32)f2bf(gelu_f(ha)) | ((u32)f2bf(gelu_f(hb2)) << 16);
            *(u32*)&hsT[swz(t, h2 >> 3) + (h2 & 7)] = pk;
        }
        #pragma unroll
        for (int r = 0; r < 2; ++r) {
            int u = t + r * 256; int e = u >> 3, c8 = u & 7;
            *(uint4*)&wl[swz(e, c8)] = *(const uint4*)(W2bf + e * 128 + half * 64 + c8 * 8);
        }
        __syncthreads();
        #pragma unroll
        for (int ks = 0; ks < 2; ++ks) {
            U8 af[4], bf[4];
            #pragma unroll
            for (int mt = 0; mt < 4; ++mt)
                af[mt].u = *(const uint4*)&hsT[swz(px0 + mt*16 + m, ks*4 + qd)];
            #pragma unroll
            for (int nt = 0; nt < 4; ++nt)
                bf[nt].u = *(const uint4*)&wl[swz(nt*16 + m, ks*4 + qd)];
            #pragma unroll
            for (int mt = 0; mt < 4; ++mt)
                #pragma unroll
                for (int nt = 0; nt < 4; ++nt)
                    acc[mt][nt] = __builtin_amdgcn_mfma_f32_16x16x32_bf16(
                        af[mt].b, bf[nt].b, acc[mt][nt], 0, 0, 0);
        }
    }
    __syncthreads();
    // ---- instance-norm stats of d -> global murs (for layer-0 attention) --
    float sv[4], qv[4];
    #pragma unroll
    for (int nt = 0; nt < 4; ++nt) {
        float ss = 0.f, qq = 0.f;
        #pragma unroll
        for (int mt = 0; mt < 4; ++mt)
            #pragma unroll
            for (int r = 0; r < 4; ++r) { float xx = acc[mt][nt][r]; ss += xx; qq = fmaf(xx, xx, qq); }
        ss += __shfl_xor(ss, 16); ss += __shfl_xor(ss, 32);
        qq += __shfl_xor(qq, 16); qq += __shfl_xor(qq, 32);
        sv[nt] = ss; qv[nt] = qq;
    }
    float* sarr = (float*)smem;        // [64 ch][4 wv] sums, then +256 sq-sums
    if (qd == 0) {
        #pragma unroll
        for (int nt = 0; nt < 4; ++nt) {
            sarr[(nt*16 + m)*4 + wv] = sv[nt];
            sarr[256 + (nt*16 + m)*4 + wv] = qv[nt];
        }
    }
    __syncthreads();
    if (t < 64) {
        float ss = sarr[t*4] + sarr[t*4+1] + sarr[t*4+2] + sarr[t*4+3];
        float qq = sarr[256+t*4] + sarr[256+t*4+1] + sarr[256+t*4+2] + sarr[256+t*4+3];
        float mu = ss * (1.0f/256.0f);
        float var = qq * (1.0f/256.0f) - mu * mu;
        mursg[(size_t)n * 128 + t] = mu;
        mursg[(size_t)n * 128 + 64 + t] = rsqrtf(var + 1e-5f);
    }
    __syncthreads();
    // ---- epilogue: write d (f32) ----
    float* eps = (float*)smem + wv * 2304;
    float* dp = d + (size_t)n * TOKSZ;
    #pragma unroll
    for (int ch2 = 0; ch2 < 2; ++ch2) {
        if (ch2) CBAR();
        #pragma unroll
        for (int mt = ch2*2; mt < ch2*2+2; ++mt)
            #pragma unroll
            for (int nt = 0; nt < 4; ++nt)
                #pragma unroll
                for (int r = 0; r < 4; ++r)
                    eps[((mt&1)*16 + qd*4 + r) * 68 + nt*16 + m] = acc[mt][nt][r];
        CBAR();
        #pragma unroll
        for (int j = 0; j < 8; ++j) {
            int f = l + 64*j; int row = f >> 4, c4 = f & 15;
            float4 v = *(float4*)&eps[row * 68 + c4 * 4];
            *(float4*)&dp[(px0 + ch2*32 + row) * 64 + c4 * 4] = v;
        }
    }
}

// ---------------- 128x64x64 GEMM helper (32 rows per wave, 4 waves) --------
__device__ __forceinline__ void gemm64h(const u16* xs, const u16* wl, const float* bv4,
                                        int px0w, int m, int qd, u16* dst) {
    f32x4 acc[2][4];
    #pragma unroll
    for (int nt = 0; nt < 4; ++nt) {
        float bb = bv4[nt];
        acc[0][nt] = {bb, bb, bb, bb};
        acc[1][nt] = {bb, bb, bb, bb};
    }
    #pragma unroll
    for (int ks = 0; ks < 2; ++ks) {
        U8 af[2], bfr[4];
        #pragma unroll
        for (int mi = 0; mi < 2; ++mi)
            af[mi].u = *(const uint4*)&xs[swz(px0w + mi*16 + m, ks*4 + qd)];
        #pragma unroll
        for (int nt = 0; nt < 4; ++nt)
            bfr[nt].u = *(const uint4*)&wl[swz(nt*16 + m, ks*4 + qd)];
        #pragma unroll
        for (int mi = 0; mi < 2; ++mi)
            #pragma unroll
            for (int nt = 0; nt < 4; ++nt)
                acc[mi][nt] = __builtin_amdgcn_mfma_f32_16x16x32_bf16(
                    af[mi].b, bfr[nt].b, acc[mi][nt], 0, 0, 0);
    }
    #pragma unroll
    for (int mi = 0; mi < 2; ++mi)
        #pragma unroll
        for (int nt = 0; nt < 4; ++nt)
            #pragma unroll
            for (int r = 0; r < 4; ++r) {
                int R = px0w + mi*16 + qd*4 + r, ch = nt*16 + m;
                dst[swz(R, ch >> 3) + (ch & 7)] = f2bf(acc[mi][nt][r]);
            }
}

// ---------------- fused norm(on-the-fly) + qkv proj + raw scores -----------
// grid (128 windows, 4 px-quarters); 256 thr; 8-px chunks; LDS 81920 B.
// 512 blocks -> 2 co-resident blocks/CU (R17-proven best).
__global__ __launch_bounds__(256, 2)
void scores_qkv(const float* __restrict__ dres, const float* __restrict__ mursg,
                const u16* __restrict__ Wq, const float* __restrict__ bq,
                const u16* __restrict__ Wk, const float* __restrict__ bk,
                const u16* __restrict__ Wv, const float* __restrict__ bv,
                int shifted, float* __restrict__ Ap, u16* __restrict__ vbuf) {
    extern __shared__ char smem[];
    u16* xs  = (u16*)smem;              // [128 rows=tok*8+pxl][64] swz; xhat then v
    u16* qls = (u16*)(smem + 16384);    // q chunk
    u16* kls = (u16*)(smem + 32768);    // k chunk
    u16* wlq = (u16*)(smem + 49152);
    u16* wlk = (u16*)(smem + 57344);
    u16* wlv = (u16*)(smem + 65536);
    float* mloc = (float*)(smem + 73728);   // [16 tok][128] mu|rs
    int w = blockIdx.x, qtr = blockIdx.y, t = threadIdx.x;
    int wv = t >> 6, l = t & 63, m = l & 15, qd = l >> 4;
    int px0w = wv * 32;
    // staging token indices: each thread touches toks {wv, wv+4, wv+8, wv+12}
    int nst[4];
    #pragma unroll
    for (int i8 = 0; i8 < 4; ++i8) {
        int nn = w * 16 + (4 * i8 + wv);
        nst[i8] = shifted ? shift_tok(nn) : nn;
    }
    // mloc load: 2048 floats (inline shift_tok, once per kernel)
    #pragma unroll
    for (int r = 0; r < 8; ++r) {
        int u = t + r * 256;
        int nn = w * 16 + (u >> 7);
        int ni = shifted ? shift_tok(nn) : nn;
        mloc[u] = mursg[(size_t)ni * 128 + (u & 127)];
    }
    #pragma unroll
    for (int r = 0; r < 2; ++r) {
        int u = t + r * 256; int e = u >> 3, c8 = u & 7;
        *(uint4*)&wlq[swz(e, c8)] = *(const uint4*)(Wq + e * 64 + c8 * 8);
        *(uint4*)&wlk[swz(e, c8)] = *(const uint4*)(Wk + e * 64 + c8 * 8);
        *(uint4*)&wlv[swz(e, c8)] = *(const uint4*)(Wv + e * 64 + c8 * 8);
    }
    float bqv[4], bkv[4], bvv[4];
    #pragma unroll
    for (int nt = 0; nt < 4; ++nt) {
        bqv[nt] = bq[nt*16 + m]; bkv[nt] = bk[nt*16 + m]; bvv[nt] = bv[nt*16 + m];
    }
    f32x4 sacc = {0.f, 0.f, 0.f, 0.f};
    __syncthreads();
    for (int ch = 0; ch < 8; ++ch) {
        int pxb = qtr * 64 + ch * 8;
        // stage + normalize chunk: 16 tok x 8 px x 64 ch (fp32 -> bf16 xhat)
        #pragma unroll
        for (int i8 = 0; i8 < 4; ++i8) {
            int u = t + i8 * 256; int row = u >> 3, c8 = u & 7;
            int pxl = row & 7;
            int tok = 4 * i8 + wv;          // == row >> 3
            const float4* gp = (const float4*)
                (dres + (size_t)nst[i8] * TOKSZ + (size_t)(pxb + pxl) * 64 + c8 * 8);
            float4 f0 = gp[0], f1 = gp[1];
            const float4* mp = (const float4*)&mloc[tok * 128 + c8 * 8];
            float4 mu0 = mp[0], mu1 = mp[1];
            const float4* rp = (const float4*)&mloc[tok * 128 + 64 + c8 * 8];
            float4 rs0 = rp[0], rs1 = rp[1];
            uint4 o;
            o.x = (u32)f2bf((f0.x-mu0.x)*rs0.x) | ((u32)f2bf((f0.y-mu0.y)*rs0.y) << 16);
            o.y = (u32)f2bf((f0.z-mu0.z)*rs0.z) | ((u32)f2bf((f0.w-mu0.w)*rs0.w) << 16);
            o.z = (u32)f2bf((f1.x-mu1.x)*rs1.x) | ((u32)f2bf((f1.y-mu1.y)*rs1.y) << 16);
            o.w = (u32)f2bf((f1.z-mu1.z)*rs1.z) | ((u32)f2bf((f1.w-mu1.w)*rs1.w) << 16);
            *(uint4*)&xs[swz(row, c8)] = o;
        }
        __syncthreads();
        // q,k GEMMs -> qls/kls; v GEMM overwrites own wave's xs rows (safe:
        // each wave's A-frag reads only rows [px0w,px0w+32), scatter same range)
        gemm64h(xs, wlq, bqv, px0w, m, qd, qls);
        gemm64h(xs, wlk, bkv, px0w, m, qd, kls);
        gemm64h(xs, wlv, bvv, px0w, m, qd, xs);
        __syncthreads();
        // raw scores: wave wv = head; K = 2px x 16ch per mfma; 4 px-pairs
        #pragma unroll
        for (int p2 = 0; p2 < 4; ++p2) {
            U8 af, bfr;
            int row = m * 8 + p2 * 2 + (qd >> 1);
            int c8 = wv * 2 + (qd & 1);
            af.u  = *(const uint4*)&qls[swz(row, c8)];
            bfr.u = *(const uint4*)&kls[swz(row, c8)];
            sacc = __builtin_amdgcn_mfma_f32_16x16x32_bf16(af.b, bfr.b, sacc, 0, 0, 0);
        }
        // v chunk -> global
        #pragma unroll
        for (int i8 = 0; i8 < 4; ++i8) {
            int u = t + i8 * 256; int row = u >> 3, c8 = u & 7;
            int pxl = row & 7;
            *(uint4*)(vbuf + (size_t)nst[i8] * 16384 + (size_t)(pxb + pxl) * 64 + c8 * 8)
                = *(const uint4*)&xs[swz(row, c8)];
        }
        __syncthreads();                // WAR: next stage overwrites xs
    }
    float* ap = Ap + (size_t)qtr * 131072 + ((size_t)w * 4 + wv) * 256;
    #pragma unroll
    for (int r = 0; r < 4; ++r)
        ap[(qd * 4 + r) * 16 + m] = sacc[r] * (1.0f / 1024.0f);
}

// ---------------- fused softmax + A@v + Wo + residual + MLP + murs ---------
// LDS exactly 40960; launch_bounds (256,2); As/nis hoisted to registers in
// the A@v loop (c8/h are loop-invariant: 256 = 0 mod 8).
__global__ __launch_bounds__(256, 2)
void wo_mlp(const u16* __restrict__ vb, const float* __restrict__ Ap,
            const u16* __restrict__ Wo, const float* __restrict__ bo,
            const u16* __restrict__ W1, const float* __restrict__ b1,
            const u16* __restrict__ W2, const float* __restrict__ b2,
            int shifted, float* __restrict__ dres, float* __restrict__ mursg,
            int wmu) {
    extern __shared__ char smem[];
    u16* xs = (u16*)smem;               // [256][64] swz: o-tile / xhat / h
    u16* wl = (u16*)(smem + 32768);     // [64][64] swz (Wo/W1/W2, loaded late)
    float* As = (float*)(smem + 32768); // [4 heads][16 j] (pre-Wo alias)
    int*  nis = (int*)(smem + 33792);   // 16 (pre-Wo alias)
    float* sarr = (float*)(smem + 32768);   // stats alias of wl
    float* murs2 = (float*)smem;            // stats alias of xs[0,512)
    int bid = blockIdx.x;
    int qg = bid >> 7, r7 = bid & 127;
    int n = ((qg << 3) + (r7 & 7)) * 16 + (r7 >> 3);
    int t = threadIdx.x;
    int wv = t >> 6, l = t & 63, m = l & 15, qd = l >> 4;
    int px0 = wv * 64;
    int w = n >> 4, i = n & 15;
    int no = shifted ? shift_tok(n) : n;
    int rbase = l >> 4, c4l = l & 15;
    if (t < 16) { int nn = w * 16 + t; nis[t] = shifted ? shift_tok(nn) : nn; }
    if (t >= 64 && t < 128) {
        int u = t - 64; int h = u >> 4, j = u & 15;
        size_t ai = ((size_t)(w * 4 + h)) * 256 + i * 16 + j;
        float sc = (Ap[ai] + Ap[131072 + ai] + Ap[262144 + ai] + Ap[393216 + ai])
                   * (1.0f / 1024.0f);
        float mx = sc;
        #pragma unroll
        for (int off = 1; off < 16; off <<= 1) mx = fmaxf(mx, __shfl_xor(mx, off, 16));
        float e = expf(sc - mx);
        float ssum = e;
        #pragma unroll
        for (int off = 1; off < 16; off <<= 1) ssum += __shfl_xor(ssum, off, 16);
        As[u] = e / ssum;
    }
    __syncthreads();
    // hoist per-thread constants: c8/h invariant across r (256 % 8 == 0)
    int c8o = t & 7, ho = c8o >> 1;
    float awv[16];
    int njo[16];
    #pragma unroll
    for (int j = 0; j < 16; ++j) { awv[j] = As[ho * 16 + j]; njo[j] = nis[j]; }
    // o-tile = A @ v, written into xs (bf16, swizzled)
    #pragma unroll
    for (int r = 0; r < 8; ++r) {
        int idx = r * 256 + t;
        int px = idx >> 3;
        float a0=0,a1=0,a2=0,a3=0,a4=0,a5=0,a6=0,a7=0;
        #pragma unroll
        for (int j = 0; j < 16; ++j) {
            const u16* src = vb + (size_t)njo[j] * 16384 + (size_t)px * 64 + c8o * 8;
            uint4 pv = *(const uint4*)src;
            float aw = awv[j];
            a0 = fmaf(aw, __uint_as_float(pv.x << 16), a0);
            a1 = fmaf(aw, __uint_as_float(pv.x & 0xFFFF0000u), a1);
            a2 = fmaf(aw, __uint_as_float(pv.y << 16), a2);
            a3 = fmaf(aw, __uint_as_float(pv.y & 0xFFFF0000u), a3);
            a4 = fmaf(aw, __uint_as_float(pv.z << 16), a4);
            a5 = fmaf(aw, __uint_as_float(pv.z & 0xFFFF0000u), a5);
            a6 = fmaf(aw, __uint_as_float(pv.w << 16), a6);
            a7 = fmaf(aw, __uint_as_float(pv.w & 0xFFFF0000u), a7);
        }
        uint4 o;
        o.x = (u32)f2bf(a0) | ((u32)f2bf(a1) << 16);
        o.y = (u32)f2bf(a2) | ((u32)f2bf(a3) << 16);
        o.z = (u32)f2bf(a4) | ((u32)f2bf(a5) << 16);
        o.w = (u32)f2bf(a6) | ((u32)f2bf(a7) << 16);
        *(uint4*)&xs[swz(px, c8o)] = o;
    }
    __syncthreads();                     // o-tile done; As/nis dead
    #pragma unroll
    for (int r = 0; r < 2; ++r) {
        int u = t + r * 256;
        int e = u >> 3, c8 = u & 7;
        *(uint4*)&wl[swz(e, c8)] = *(const uint4*)(Wo + e * 64 + c8 * 8);
    }
    __syncthreads();
    // GEMM: attnout = Wo · o + bo
    f32x4 acc[4][4];
    #pragma unroll
    for (int nt = 0; nt < 4; ++nt) {
        float bb = bo[nt * 16 + m];
        #pragma unroll
        for (int mt = 0; mt < 4; ++mt) acc[mt][nt] = {bb, bb, bb, bb};
    }
    #pragma unroll
    for (int ks = 0; ks < 2; ++ks) {
        U8 af[4], bf[4];
        #pragma unroll
        for (int mt = 0; mt < 4; ++mt)
            af[mt].u = *(const uint4*)&xs[swz(px0 + mt*16 + m, ks*4 + qd)];
        #pragma unroll
        for (int nt = 0; nt < 4; ++nt)
            bf[nt].u = *(const uint4*)&wl[swz(nt*16 + m, ks*4 + qd)];
        #pragma unroll
        for (int mt = 0; mt < 4; ++mt)
            #pragma unroll
            for (int nt = 0; nt < 4; ++nt)
                acc[mt][nt] = __builtin_amdgcn_mfma_f32_16x16x32_bf16(
                    af[mt].b, bf[nt].b, acc[mt][nt], 0, 0, 0);
    }
    __syncthreads();                     // xs/wl dead -> alias eps
    // handoff: xv = d[no] + attnout (registers, mlp layout)
    float* eps = (float*)smem + wv * 2304;
    float* dp = dres + (size_t)no * TOKSZ;
    float4 xv[2][8];
    #pragma unroll
    for (int ch2 = 0; ch2 < 2; ++ch2) {
        if (ch2) CBAR();
        #pragma unroll
        for (int mt = ch2*2; mt < ch2*2+2; ++mt)
            #pragma unroll
            for (int nt = 0; nt < 4; ++nt)
                #pragma unroll
                for (int r = 0; r < 4; ++r)
                    eps[((mt&1)*16 + qd*4 + r) * 68 + nt*16 + m] = acc[mt][nt][r];
        CBAR();
        #pragma unroll
        for (int j = 0; j < 8; ++j) {
            int row = rbase + 4*j;
            float4 dv = *(float4*)&eps[row * 68 + c4l * 4];
            float4 gv = *(const float4*)&dp[(px0 + ch2*32 + row) * 64 + c4l * 4];
            gv.x += dv.x; gv.y += dv.y; gv.z += dv.z; gv.w += dv.w;
            xv[ch2][j] = gv;
        }
    }
    __syncthreads();                     // eps dead before sarr reuse
    // ---- MLP phase: norm stats ----
    float s0=0,s1=0,s2=0,s3=0,q0=0,q1=0,q2=0,q3=0;
    #pragma unroll
    for (int ch2 = 0; ch2 < 2; ++ch2)
        #pragma unroll
        for (int j = 0; j < 8; ++j) {
            float4 v = xv[ch2][j];
            s0 += v.x; q0 = fmaf(v.x, v.x, q0);
            s1 += v.y; q1 = fmaf(v.y, v.y, q1);
            s2 += v.z; q2 = fmaf(v.z, v.z, q2);
            s3 += v.w; q3 = fmaf(v.w, v.w, q3);
        }
    int cb = 4 * c4l, g = t >> 4;
    float* qarr = sarr + 1024;
    sarr[(cb+0)*16+g]=s0; sarr[(cb+1)*16+g]=s1; sarr[(cb+2)*16+g]=s2; sarr[(cb+3)*16+g]=s3;
    qarr[(cb+0)*16+g]=q0; qarr[(cb+1)*16+g]=q1; qarr[(cb+2)*16+g]=q2; qarr[(cb+3)*16+g]=q3;
    __syncthreads();
    if (t < 64) {
        float ss = 0.f, qq = 0.f;
        #pragma unroll
        for (int gg = 0; gg < 16; ++gg) { ss += sarr[t*16+gg]; qq += qarr[t*16+gg]; }
        float mu = ss * (1.0f/256.0f);
        float var = qq * (1.0f/256.0f) - mu * mu;
        murs2[t] = mu; murs2[64 + t] = rsqrtf(var + 1e-5f);
    }
    __syncthreads();
    float m0 = murs2[cb], m1 = murs2[cb+1], m2 = murs2[cb+2], m3 = murs2[cb+3];
    float r0 = murs2[64+cb], r1 = murs2[64+cb+1], r2 = murs2[64+cb+2], r3 = murs2[64+cb+3];
    __syncthreads();                     // murs2 reads done before xs writes
    #pragma unroll
    for (int ch2 = 0; ch2 < 2; ++ch2)
        #pragma unroll
        for (int j = 0; j < 8; ++j) {
            float4 v = xv[ch2][j];
            int row = px0 + ch2*32 + rbase + 4*j;
            uint2 o;
            o.x = (u32)f2bf((v.x-m0)*r0) | ((u32)f2bf((v.y-m1)*r1) << 16);
            o.y = (u32)f2bf((v.z-m2)*r2) | ((u32)f2bf((v.w-m3)*r3) << 16);
            *(uint2*)&xs[swz(row, c4l >> 1) + (c4l & 1) * 4] = o;
        }
    #pragma unroll
    for (int r = 0; r < 2; ++r) {
        int u = t + r * 256;
        int e = u >> 3, c8 = u & 7;
        *(uint4*)&wl[swz(e, c8)] = *(const uint4*)(W1 + e * 64 + c8 * 8);
    }
    __syncthreads();
    #pragma unroll
    for (int nt = 0; nt < 4; ++nt) {
        float bb = b1[nt * 16 + m];
        #pragma unroll
        for (int mt = 0; mt < 4; ++mt) acc[mt][nt] = {bb, bb, bb, bb};
    }
    #pragma unroll
    for (int ks = 0; ks < 2; ++ks) {
        U8 af[4], bf[4];
        #pragma unroll
        for (int mt = 0; mt < 4; ++mt)
            af[mt].u = *(const uint4*)&xs[swz(px0 + mt*16 + m, ks*4 + qd)];
        #pragma unroll
        for (int nt = 0; nt < 4; ++nt)
            bf[nt].u = *(const uint4*)&wl[swz(nt*16 + m, ks*4 + qd)];
        #pragma unroll
        for (int mt = 0; mt < 4; ++mt)
            #pragma unroll
            for (int nt = 0; nt < 4; ++nt)
                acc[mt][nt] = __builtin_amdgcn_mfma_f32_16x16x32_bf16(
                    af[mt].b, bf[nt].b, acc[mt][nt], 0, 0, 0);
    }
    __syncthreads();
    #pragma unroll
    for (int nt = 0; nt < 4; ++nt) {
        int ch = nt * 16 + m;
        #pragma unroll
        for (int mt = 0; mt < 4; ++mt)
            #pragma unroll
            for (int r = 0; r < 4; ++r) {
                int R = px0 + mt*16 + qd*4 + r;
                xs[swz(R, ch >> 3) + (ch & 7)] = f2bf(gelu_f(acc[mt][nt][r]));
            }
    }
    #pragma unroll
    for (int r = 0; r < 2; ++r) {
        int u = t + r * 256;
        int e = u >> 3, c8 = u & 7;
        *(uint4*)&wl[swz(e, c8)] = *(const uint4*)(W2 + e * 64 + c8 * 8);
    }
    __syncthreads();
    #pragma unroll
    for (int nt = 0; nt < 4; ++nt) {
        float bb = b2[nt * 16 + m];
        #pragma unroll
        for (int mt = 0; mt < 4; ++mt) acc[mt][nt] = {bb, bb, bb, bb};
    }
    #pragma unroll
    for (int ks = 0; ks < 2; ++ks) {
        U8 af[4], bf[4];
        #pragma unroll
        for (int mt = 0; mt < 4; ++mt)
            af[mt].u = *(const uint4*)&xs[swz(px0 + mt*16 + m, ks*4 + qd)];
        #pragma unroll
        for (int nt = 0; nt < 4; ++nt)
            bf[nt].u = *(const uint4*)&wl[swz(nt*16 + m, ks*4 + qd)];
        #pragma unroll
        for (int mt = 0; mt < 4; ++mt)
            #pragma unroll
            for (int nt = 0; nt < 4; ++nt)
                acc[mt][nt] = __builtin_amdgcn_mfma_f32_16x16x32_bf16(
                    af[mt].b, bf[nt].b, acc[mt][nt], 0, 0, 0);
    }
    __syncthreads();
    #pragma unroll
    for (int ch2 = 0; ch2 < 2; ++ch2) {
        if (ch2) CBAR();
        #pragma unroll
        for (int mt = ch2*2; mt < ch2*2+2; ++mt)
            #pragma unroll
            for (int nt = 0; nt < 4; ++nt)
                #pragma unroll
                for (int r = 0; r < 4; ++r)
                    eps[((mt&1)*16 + qd*4 + r) * 68 + nt*16 + m] = acc[mt][nt][r];
        CBAR();
        #pragma unroll
        for (int j = 0; j < 8; ++j) {
            int row = rbase + 4*j;
            float4 dv = *(float4*)&eps[row * 68 + c4l * 4];
            float4 bs = xv[ch2][j];                   // residual from registers
            bs.x += dv.x; bs.y += dv.y; bs.z += dv.z; bs.w += dv.w;
            xv[ch2][j] = bs;                          // final d
            *(float4*)&dp[(px0 + ch2*32 + row) * 64 + c4l * 4] = bs;
        }
    }
    if (wmu) {
        __syncthreads();                // eps reads done before sarr reuse
        float t0=0,t1=0,t2=0,t3=0,u0=0,u1=0,u2=0,u3=0;
        #pragma unroll
        for (int ch2 = 0; ch2 < 2; ++ch2)
            #pragma unroll
            for (int j = 0; j < 8; ++j) {
                float4 v = xv[ch2][j];
                t0 += v.x; u0 = fmaf(v.x, v.x, u0);
                t1 += v.y; u1 = fmaf(v.y, v.y, u1);
                t2 += v.z; u2 = fmaf(v.z, v.z, u2);
                t3 += v.w; u3 = fmaf(v.w, v.w, u3);
            }
        sarr[(cb+0)*16+g]=t0; sarr[(cb+1)*16+g]=t1; sarr[(cb+2)*16+g]=t2; sarr[(cb+3)*16+g]=t3;
        qarr[(cb+0)*16+g]=u0; qarr[(cb+1)*16+g]=u1; qarr[(cb+2)*16+g]=u2; qarr[(cb+3)*16+g]=u3;
        __syncthreads();
        if (t < 64) {
            float ss = 0.f, qq = 0.f;
            #pragma unroll
            for (int gg = 0; gg < 16; ++gg) { ss += sarr[t*16+gg]; qq += qarr[t*16+gg]; }
            float mu = ss * (1.0f/256.0f);
            float var = qq * (1.0f/256.0f) - mu * mu;
            mursg[(size_t)no * 128 + t] = mu;
            mursg[(size_t)no * 128 + 64 + t] = rsqrtf(var + 1e-5f);
        }
    }
}

// ---------------- layer 3: softmax + A@v + Wo + residual + MLP + out MLP ---
// wo_mlp front (no d write) + mlp_out tail; physical token = no (shifted).
// LDS exactly 40960; launch_bounds (256,2); As/nis hoisted like wo_mlp.
__global__ __launch_bounds__(256, 2)
void wo_mlp_out(const u16* __restrict__ vb, const float* __restrict__ Ap,
                const u16* __restrict__ Wo, const float* __restrict__ bo,
                const u16* __restrict__ W1, const float* __restrict__ b1,
                const u16* __restrict__ W2, const float* __restrict__ b2,
                int shifted, const float* __restrict__ dres,
                const u16* __restrict__ oW1, const float* __restrict__ ob1,
                const float* __restrict__ oW2, const float* __restrict__ ob2,
                void* __restrict__ outp, const int* __restrict__ flag) {
    extern __shared__ char smem[];
    u16* xs = (u16*)smem;               // [256][64] swz: o-tile / xhat / h / d16
    u16* wl = (u16*)(smem + 32768);     // [64][64] swz (Wo/W1/W2/oW1)
    float* As = (float*)(smem + 32768); // [4 heads][16 j] (pre-Wo alias)
    int*  nis = (int*)(smem + 33792);   // 16 (pre-Wo alias)
    float* sarr = (float*)(smem + 32768);   // stats alias of wl
    float* murs2 = (float*)smem;            // stats alias of xs[0,512)
    int bid = blockIdx.x;
    int qg = bid >> 7, r7 = bid & 127;
    int n = ((qg << 3) + (r7 & 7)) * 16 + (r7 >> 3);
    int t = threadIdx.x;
    int wv = t >> 6, l = t & 63, m = l & 15, qd = l >> 4;
    int px0 = wv * 64;
    int w = n >> 4, i = n & 15;
    int no = shifted ? shift_tok(n) : n;
    int rbase = l >> 4, c4l = l & 15;
    if (t < 16) { int nn = w * 16 + t; nis[t] = shifted ? shift_tok(nn) : nn; }
    if (t >= 64 && t < 128) {
        int u = t - 64; int h = u >> 4, j = u & 15;
        size_t ai = ((size_t)(w * 4 + h)) * 256 + i * 16 + j;
        float sc = (Ap[ai] + Ap[131072 + ai] + Ap[262144 + ai] + Ap[393216 + ai])
                   * (1.0f / 1024.0f);
        float mx = sc;
        #pragma unroll
        for (int off = 1; off < 16; off <<= 1) mx = fmaxf(mx, __shfl_xor(mx, off, 16));
        float e = expf(sc - mx);
        float ssum = e;
        #pragma unroll
        for (int off = 1; off < 16; off <<= 1) ssum += __shfl_xor(ssum, off, 16);
        As[u] = e / ssum;
    }
    __syncthreads();
    // hoist per-thread constants
    int c8o = t & 7, ho = c8o >> 1;
    float awv[16];
    int njo[16];
    #pragma unroll
    for (int j = 0; j < 16; ++j) { awv[j] = As[ho * 16 + j]; njo[j] = nis[j]; }
    // o-tile = A @ v
    #pragma unroll
    for (int r = 0; r < 8; ++r) {
        int idx = r * 256 + t;
        int px = idx >> 3;
        float a0=0,a1=0,a2=0,a3=0,a4=0,a5=0,a6=0,a7=0;
        #pragma unroll
        for (int j = 0; j < 16; ++j) {
            const u16* src = vb + (size_t)njo[j] * 16384 + (size_t)px * 64 + c8o * 8;
            uint4 pv = *(const uint4*)src;
            float aw = awv[j];
            a0 = fmaf(aw, __uint_as_float(pv.x << 16), a0);
            a1 = fmaf(aw, __uint_as_float(pv.x & 0xFFFF0000u), a1);
            a2 = fmaf(aw, __uint_as_float(pv.y << 16), a2);
            a3 = fmaf(aw, __uint_as_float(pv.y & 0xFFFF0000u), a3);
            a4 = fmaf(aw, __uint_as_float(pv.z << 16), a4);
            a5 = fmaf(aw, __uint_as_float(pv.z & 0xFFFF0000u), a5);
            a6 = fmaf(aw, __uint_as_float(pv.w << 16), a6);
            a7 = fmaf(aw, __uint_as_float(pv.w & 0xFFFF0000u), a7);
        }
        uint4 o;
        o.x = (u32)f2bf(a0) | ((u32)f2bf(a1) << 16);
        o.y = (u32)f2bf(a2) | ((u32)f2bf(a3) << 16);
        o.z = (u32)f2bf(a4) | ((u32)f2bf(a5) << 16);
        o.w = (u32)f2bf(a6) | ((u32)f2bf(a7) << 16);
        *(uint4*)&xs[swz(px, c8o)] = o;
    }
    __syncthreads();                     // o-tile done; As/nis dead
    #pragma unroll
    for (int r = 0; r < 2; ++r) {
        int u = t + r * 256;
        int e = u >> 3, c8 = u & 7;
        *(uint4*)&wl[swz(e, c8)] = *(const uint4*)(Wo + e * 64 + c8 * 8);
    }
    __syncthreads();
    // GEMM: attnout = Wo · o + bo
    f32x4 acc[4][4];
    #pragma unroll
    for (int nt = 0; nt < 4; ++nt) {
        float bb = bo[nt * 16 + m];
        #pragma unroll
        for (int mt = 0; mt < 4; ++mt) acc[mt][nt] = {bb, bb, bb, bb};
    }
    #pragma unroll
    for (int ks = 0; ks < 2; ++ks) {
        U8 af[4], bf[4];
        #pragma unroll
        for (int mt = 0; mt < 4; ++mt)
            af[mt].u = *(const uint4*)&xs[swz(px0 + mt*16 + m, ks*4 + qd)];
        #pragma unroll
        for (int nt = 0; nt < 4; ++nt)
            bf[nt].u = *(const uint4*)&wl[swz(nt*16 + m, ks*4 + qd)];
        #pragma unroll
        for (int mt = 0; mt < 4; ++mt)
            #pragma unroll
            for (int nt = 0; nt < 4; ++nt)
                acc[mt][nt] = __builtin_amdgcn_mfma_f32_16x16x32_bf16(
                    af[mt].b, bf[nt].b, acc[mt][nt], 0, 0, 0);
    }
    __syncthreads();                     // xs/wl dead -> alias eps
    // handoff: xv = d[no] + attnout (registers, mlp layout)
    float* eps = (float*)smem + wv * 2304;
    const float* dp = dres + (size_t)no * TOKSZ;
    float4 xv[2][8];
    #pragma unroll
    for (int ch2 = 0; ch2 < 2; ++ch2) {
        if (ch2) CBAR();
        #pragma unroll
        for (int mt = ch2*2; mt < ch2*2+2; ++mt)
            #pragma unroll
            for (int nt = 0; nt < 4; ++nt)
                #pragma unroll
                for (int r = 0; r < 4; ++r)
                    eps[((mt&1)*16 + qd*4 + r) * 68 + nt*16 + m] = acc[mt][nt][r];
        CBAR();
        #pragma unroll
        for (int j = 0; j < 8; ++j) {
            int row = rbase + 4*j;
            float4 dv = *(float4*)&eps[row * 68 + c4l * 4];
            float4 gv = *(const float4*)&dp[(px0 + ch2*32 + row) * 64 + c4l * 4];
            gv.x += dv.x; gv.y += dv.y; gv.z += dv.z; gv.w += dv.w;
            xv[ch2][j] = gv;
        }
    }
    __syncthreads();                     // eps dead before sarr reuse
    // ---- MLP phase: norm stats ----
    float s0=0,s1=0,s2=0,s3=0,q0=0,q1=0,q2=0,q3=0;
    #pragma unroll
    for (int ch2 = 0; ch2 < 2; ++ch2)
        #pragma unroll
        for (int j = 0; j < 8; ++j) {
            float4 v = xv[ch2][j];
            s0 += v.x; q0 = fmaf(v.x, v.x, q0);
            s1 += v.y; q1 = fmaf(v.y, v.y, q1);
            s2 += v.z; q2 = fmaf(v.z, v.z, q2);
            s3 += v.w; q3 = fmaf(v.w, v.w, q3);
        }
    int cb = 4 * c4l, g = t >> 4;
    float* qarr = sarr + 1024;
    sarr[(cb+0)*16+g]=s0; sarr[(cb+1)*16+g]=s1; sarr[(cb+2)*16+g]=s2; sarr[(cb+3)*16+g]=s3;
    qarr[(cb+0)*16+g]=q0; qarr[(cb+1)*16+g]=q1; qarr[(cb+2)*16+g]=q2; qarr[(cb+3)*16+g]=q3;
    __syncthreads();
    if (t < 64) {
        float ss = 0.f, qq = 0.f;
        #pragma unroll
        for (int gg = 0; gg < 16; ++gg) { ss += sarr[t*16+gg]; qq += qarr[t*16+gg]; }
        float mu = ss * (1.0f/256.0f);
        float var = qq * (1.0f/256.0f) - mu * mu;
        murs2[t] = mu; murs2[64 + t] = rsqrtf(var + 1e-5f);
    }
    __syncthreads();
    float m0 = murs2[cb], m1 = murs2[cb+1], m2 = murs2[cb+2], m3 = murs2[cb+3];
    float r0 = murs2[64+cb], r1 = murs2[64+cb+1], r2 = murs2[64+cb+2], r3 = murs2[64+cb+3];
    __syncthreads();                     // murs2 reads done before xs writes
    #pragma unroll
    for (int ch2 = 0; ch2 < 2; ++ch2)
        #pragma unroll
        for (int j = 0; j < 8; ++j) {
            float4 v = xv[ch2][j];
            int row = px0 + ch2*32 + rbase + 4*j;
            uint2 o;
            o.x = (u32)f2bf((v.x-m0)*r0) | ((u32)f2bf((v.y-m1)*r1) << 16);
            o.y = (u32)f2bf((v.z-m2)*r2) | ((u32)f2bf((v.w-m3)*r3) << 16);
            *(uint2*)&xs[swz(row, c4l >> 1) + (c4l & 1) * 4] = o;
        }
    #pragma unroll
    for (int r = 0; r < 2; ++r) {
        int u = t + r * 256;
        int e = u >> 3, c8 = u & 7;
        *(uint4*)&wl[swz(e, c8)] = *(const uint4*)(W1 + e * 64 + c8 * 8);
    }
    __syncthreads();
    #pragma unroll
    for (int nt = 0; nt < 4; ++nt) {
        float bb = b1[nt * 16 + m];
        #pragma unroll
        for (int mt = 0; mt < 4; ++mt) acc[mt][nt] = {bb, bb, bb, bb};
    }
    #pragma unroll
    for (int ks = 0; ks < 2; ++ks) {
        U8 af[4], bf[4];
        #pragma unroll
        for (int mt = 0; mt < 4; ++mt)
            af[mt].u = *(const uint4*)&xs[swz(px0 + mt*16 + m, ks*4 + qd)];
        #pragma unroll
        for (int nt = 0; nt < 4; ++nt)
            bf[nt].u = *(const uint4*)&wl[swz(nt*16 + m, ks*4 + qd)];
        #pragma unroll
        for (int mt = 0; mt < 4; ++mt)
            #pragma unroll
            for (int nt = 0; nt < 4; ++nt)
                acc[mt][nt] = __builtin_amdgcn_mfma_f32_16x16x32_bf16(
                    af[mt].b, bf[nt].b, acc[mt][nt], 0, 0, 0);
    }
    __syncthreads();
    #pragma unroll
    for (int nt = 0; nt < 4; ++nt) {
        int ch = nt * 16 + m;
        #pragma unroll
        for (int mt = 0; mt < 4; ++mt)
            #pragma unroll
            for (int r = 0; r < 4; ++r) {
                int R = px0 + mt*16 + qd*4 + r;
                xs[swz(R, ch >> 3) + (ch & 7)] = f2bf(gelu_f(acc[mt][nt][r]));
            }
    }
    #pragma unroll
    for (int r = 0; r < 2; ++r) {
        int u = t + r * 256;
        int e = u >> 3, c8 = u & 7;
        *(uint4*)&wl[swz(e, c8)] = *(const uint4*)(W2 + e * 64 + c8 * 8);
    }
    __syncthreads();
    #pragma unroll
    for (int nt = 0; nt < 4; ++nt) {
        float bb = b2[nt * 16 + m];
        #pragma unroll
        for (int mt = 0; mt < 4; ++mt) acc[mt][nt] = {bb, bb, bb, bb};
    }
    #pragma unroll
    for (int ks = 0; ks < 2; ++ks) {
        U8 af[4], bf[4];
        #pragma unroll
        for (int mt = 0; mt < 4; ++mt)
            af[mt].u = *(const uint4*)&xs[swz(px0 + mt*16 + m, ks*4 + qd)];
        #pragma unroll
        for (int nt = 0; nt < 4; ++nt)
            bf[nt].u = *(const uint4*)&wl[swz(nt*16 + m, ks*4 + qd)];
        #pragma unroll
        for (int mt = 0; mt < 4; ++mt)
            #pragma unroll
            for (int nt = 0; nt < 4; ++nt)
                acc[mt][nt] = __builtin_amdgcn_mfma_f32_16x16x32_bf16(
                    af[mt].b, bf[nt].b, acc[mt][nt], 0, 0, 0);
    }
    __syncthreads();
    // residual add in registers; final d stays local (never written to HBM)
    #pragma unroll
    for (int ch2 = 0; ch2 < 2; ++ch2) {
        if (ch2) CBAR();
        #pragma unroll
        for (int mt = ch2*2; mt < ch2*2+2; ++mt)
            #pragma unroll
            for (int nt = 0; nt < 4; ++nt)
                #pragma unroll
                for (int r = 0; r < 4; ++r)
                    eps[((mt&1)*16 + qd*4 + r) * 68 + nt*16 + m] = acc[mt][nt][r];
        CBAR();
        #pragma unroll
        for (int j = 0; j < 8; ++j) {
            int row = rbase + 4*j;
            float4 dv = *(float4*)&eps[row * 68 + c4l * 4];
            float4 bs = xv[ch2][j];
            bs.x += dv.x; bs.y += dv.y; bs.z += dv.z; bs.w += dv.w;
            xv[ch2][j] = bs;
        }
    }
    __syncthreads();                    // eps dead; stage d(bf16) -> xs
    #pragma unroll
    for (int ch2 = 0; ch2 < 2; ++ch2)
        #pragma unroll
        for (int j = 0; j < 8; ++j) {
            float4 v = xv[ch2][j];
            int row = px0 + ch2*32 + rbase + 4*j;
            uint2 o;
            o.x = (u32)f2bf(v.x) | ((u32)f2bf(v.y) << 16);
            o.y = (u32)f2bf(v.z) | ((u32)f2bf(v.w) << 16);
            *(uint2*)&xs[swz(row, c4l >> 1) + (c4l & 1) * 4] = o;
        }
    __syncthreads();
    // ---- output MLP: 64 -> 128(gelu) -> 1, M-halved GEMM passes ----
    float val[4][4];
    #pragma unroll
    for (int mt = 0; mt < 4; ++mt)
        #pragma unroll
        for (int r = 0; r < 4; ++r) val[mt][r] = 0.f;
    for (int nh = 0; nh < 2; ++nh) {
        if (nh) __syncthreads();
        #pragma unroll
        for (int r = 0; r < 2; ++r) {
            int u = t + r * 256;
            int e = u >> 3, c8 = u & 7;
            *(uint4*)&wl[swz(e, c8)] = *(const uint4*)(oW1 + (size_t)nh * 4096 + e * 64 + c8 * 8);
        }
        __syncthreads();
        float w2v[4];
        #pragma unroll
        for (int nt = 0; nt < 4; ++nt) w2v[nt] = oW2[nh * 64 + nt * 16 + m];
        #pragma unroll
        for (int mtp = 0; mtp < 2; ++mtp) {
            f32x4 oacc[2][4];
            #pragma unroll
            for (int nt = 0; nt < 4; ++nt) {
                float bb = ob1[nh * 64 + nt * 16 + m];
                oacc[0][nt] = {bb, bb, bb, bb};
                oacc[1][nt] = {bb, bb, bb, bb};
            }
            #pragma unroll
            for (int ks = 0; ks < 2; ++ks) {
                U8 af[2], bf[4];
                #pragma unroll
                for (int mi = 0; mi < 2; ++mi)
                    af[mi].u = *(const uint4*)&xs[swz(px0 + (2*mtp+mi)*16 + m, ks*4 + qd)];
                #pragma unroll
                for (int nt = 0; nt < 4; ++nt)
                    bf[nt].u = *(const uint4*)&wl[swz(nt*16 + m, ks*4 + qd)];
                #pragma unroll
                for (int mi = 0; mi < 2; ++mi)
                    #pragma unroll
                    for (int nt = 0; nt < 4; ++nt)
                        oacc[mi][nt] = __builtin_amdgcn_mfma_f32_16x16x32_bf16(
                            af[mi].b, bf[nt].b, oacc[mi][nt], 0, 0, 0);
            }
            #pragma unroll
            for (int mi = 0; mi < 2; ++mi)
                #pragma unroll
                for (int r = 0; r < 4; ++r) {
                    float p = 0.f;
                    #pragma unroll
                    for (int nt = 0; nt < 4; ++nt)
                        p = fmaf(gelu_f(oacc[mi][nt][r]), w2v[nt], p);
                    val[2*mtp + mi][r] += p;
                }
        }
    }
    __syncthreads();
    float* red = (float*)smem;                 // [256][17]
    #pragma unroll
    for (int mt = 0; mt < 4; ++mt)
        #pragma unroll
        for (int r = 0; r < 4; ++r)
            red[(px0 + mt*16 + qd*4 + r) * 17 + m] = val[mt][r];
    __syncthreads();
    float a = ob2[0];
    #pragma unroll
    for (int j = 0; j < 16; ++j) a += red[t * 17 + j];
    // output coords from PHYSICAL token no
    int wp = no >> 4, sp = no & 15;
    int b = wp >> 4, wy = (wp >> 2) & 3, wx = wp & 3;
    int ty = sp >> 2, tx = sp & 3;
    int y = ((wy << 2) + ty) * 16 + (t >> 4);
    int x = ((wx << 2) + tx) * 16 + (t & 15);
    size_t oi = (size_t)b * 65536 + (size_t)y * 256 + (size_t)x;
    if (*flag) ((float*)outp)[oi] = a;
    else       ((u16*)outp)[oi] = f2bf(a);
}

// ---------------- host launch ----------------------------------------------
extern "C" void kernel_launch(void* const* d_in, const int* in_sizes, int n_in,
                              void* d_out, int out_size, void* d_ws, size_t ws_size,
                              hipStream_t stream) {
    (void)n_in; (void)out_size; (void)ws_size;
    const int* pdsy = (const int*)d_in[21];
    const int* pdsx = (const int*)d_in[22];

    // layout (~205 MB, under proven 235.65 MB); Ap 4 quarter-partials
    char* wsb = (char*)d_ws;
    float* bufd  = (float*)wsb;                       // 134217728
    u16*  vbuf   = (u16*)(wsb + 134217728ull);        // 67108864
    float* Ap    = (float*)(wsb + 201326592ull);      // 2097152 (4 x 131072 fl)
    float* mursg = (float*)(wsb + 203423744ull);      // 1048576 ([tok][mu64|rs64])
    float* wbufA = (float*)(wsb + 204472320ull);      // 10752
    u16* wbuf16  = (u16*)(wsb + 204483072ull);        // ~234752
    int* flag    = (int*)(wsb + 204718080ull);

    const int f32set[12] = {1, 2, 4, 6, 8, 10, 12, 14, 16, 18, 19, 20};
    WArgs wa;
    int off16[NWT + 1]; off16[0] = 0;
    int c32[NWT + 1];
    int fo = 0;
    for (int i = 0; i < NWT; ++i) {
        int di = i + 1;
        wa.src[i] = d_in[di];
        off16[i + 1] = off16[i] + in_sizes[di];
        wa.off16[i] = off16[i];
        int isf = 0;
        for (int j = 0; j < 12; ++j) if (f32set[j] == di) isf = 1;
        wa.f32o[i] = isf ? fo : -1;
        c32[di] = isf ? fo : -1;
        if (isf) fo += in_sizes[di];
    }
    wa.off16[NWT] = off16[NWT];

    detect_kernel<<<1, 64, 0, stream>>>((const u16*)d_in[1], flag);
    cvt_weights<<<(off16[NWT] + 255) / 256, 256, 0, stream>>>(wa, flag, wbufA, wbuf16);

    const float* f_inpW1 = wbufA + c32[1];
    const float* f_inpb1 = wbufA + c32[2];
    const float* f_inpb2 = wbufA + c32[4];
    const float* f_bq  = wbufA + c32[6];
    const float* f_bk  = wbufA + c32[8];
    const float* f_bv  = wbufA + c32[10];
    const float* f_bo  = wbufA + c32[12];
    const float* f_mb1 = wbufA + c32[14];
    const float* f_mb2 = wbufA + c32[16];
    const float* f_ob1 = wbufA + c32[18];
    const float* f_oW2 = wbufA + c32[19];
    const float* f_ob2 = wbufA + c32[20];
    const u16* h_inpW2 = wbuf16 + off16[2];
    const u16* h_Wq  = wbuf16 + off16[4];
    const u16* h_Wk  = wbuf16 + off16[6];
    const u16* h_Wv  = wbuf16 + off16[8];
    const u16* h_Wo  = wbuf16 + off16[10];
    const u16* h_mW1 = wbuf16 + off16[12];
    const u16* h_mW2 = wbuf16 + off16[14];
    const u16* h_oW1 = wbuf16 + off16[16];

    embed_mfma<<<NTOK, 256, 40960, stream>>>(d_in[0], flag, f_inpW1, f_inpb1,
                                             h_inpW2, f_inpb2, pdsy, pdsx,
                                             bufd, mursg);

    for (int l = 0; l < 4; ++l) {
        int sh = l & 1;
        const u16* Wql = h_Wq + l * 4096;  const float* bql = f_bq + l * 64;
        const u16* Wkl = h_Wk + l * 4096;  const float* bkl = f_bk + l * 64;
        const u16* Wvl = h_Wv + l * 4096;  const float* bvl = f_bv + l * 64;
        const u16* Wol = h_Wo + l * 4096;  const float* bol = f_bo + l * 64;
        const u16* W1l = h_mW1 + l * 4096; const float* b1l = f_mb1 + l * 64;
        const u16* W2l = h_mW2 + l * 4096; const float* b2l = f_mb2 + l * 64;

        scores_qkv<<<dim3(128, 4), 256, 81920, stream>>>(
            bufd, mursg, Wql, bql, Wkl, bkl, Wvl, bvl, sh, Ap, vbuf);
        if (l < 3) {
            wo_mlp<<<NTOK, 256, 40960, stream>>>(vbuf, Ap, Wol, bol,
                                                 W1l, b1l, W2l, b2l,
                                                 sh, bufd, mursg, 1);
        } else {
            wo_mlp_out<<<NTOK, 256, 40960, stream>>>(vbuf, Ap, Wol, bol,
                                                     W1l, b1l, W2l, b2l,
                                                     sh, bufd,
                                                     h_oW1, f_ob1, f_oW2, f_ob2,
                                                     d_out, flag);
        }
    }
}